// Round 5
// baseline (263.739 us; speedup 1.0000x reference)
//
#include <hip/hip_runtime.h>
#include <hip/hip_bf16.h>

// Problem constants
#define NN 16
#define CF 768
#define CC 64
#define HH 56
#define WW 56
#define SS 40
#define PP (SS*SS)          // 1600 positions per image
#define PPAD 1664           // padded to 13*128 for 128-tile GEMM
#define NPT (NN*PP)         // 25600
#define NPTP (NN*PPAD)      // 26624
#define HWP (HH*WW)         // 3136

typedef __attribute__((ext_vector_type(8))) short short8;
typedef __attribute__((ext_vector_type(4))) float f32x4;

typedef const __attribute__((address_space(1))) void* gas_p;
typedef __attribute__((address_space(3))) void* las_p;

__device__ __forceinline__ unsigned f2b(float f) {
    __hip_bfloat16 b = __float2bfloat16(f);
    return (unsigned)*(unsigned short*)&b;
}
__device__ __forceinline__ float bup(unsigned u, int hi) {
    unsigned bits = hi ? (u & 0xffff0000u) : (u << 16);
    return __uint_as_float(bits);
}

// Shared bilinear helper — EXACT same arithmetic as validated round-1 kernel.
__device__ __forceinline__ void bilin(float gx, float gy,
    int& o00, int& o01, int& o10, int& o11,
    float& w00, float& w01, float& w10, float& w11)
{
    float x = (gx + 1.f) * 0.5f * (float)(WW - 1);
    float y = (gy + 1.f) * 0.5f * (float)(HH - 1);
    x = fminf(fmaxf(x, 0.f), (float)(WW - 1));
    y = fminf(fmaxf(y, 0.f), (float)(HH - 1));
    float xf = floorf(x), yf = floorf(y);
    int x0 = (int)xf, y0 = (int)yf;
    int x1 = min(x0 + 1, WW - 1), y1 = min(y0 + 1, HH - 1);
    float wx = x - xf, wy = y - yf;
    w00 = (1.f-wx)*(1.f-wy); w01 = wx*(1.f-wy); w10 = (1.f-wx)*wy; w11 = wx*wy;
    o00 = y0*WW + x0; o01 = y0*WW + x1; o10 = y1*WW + x0; o11 = y1*WW + x1;
}

// ---------------------------------------------------------------------------
// Kernel 1: sampling — VERBATIM round-4 (validated, ~80us): per-channel
// pipeline, 2x16KB double-buffered LDS plane via global_load_lds, counted
// vmcnt(4), bilinear meta computed once.
// ---------------------------------------------------------------------------
__global__ __launch_bounds__(256) void k_sample(
    const float* __restrict__ f0, const float* __restrict__ f1,
    const float* __restrict__ c0in, const float* __restrict__ c1in,
    const float* __restrict__ g0, const float* __restrict__ g1,
    float* __restrict__ nrmF, float* __restrict__ nrmC,
    short* __restrict__ OF0, short* __restrict__ OF1,
    short* __restrict__ OC0, short* __restrict__ OC1)
{
    // decode quarter-interleaved flat index (identical to validated kernel)
    const int flat = blockIdx.x;                       // [0, 3328)
    const int q    = (flat >> 3) & 3;                  // quarter
    const int u    = ((flat >> 5) << 3) | (flat & 7);  // [0, 832)
    const int set  = u / 416;                          // 26*16 = 416
    const int rem  = u % 416;
    const int n    = rem / 26;
    const int v    = rem % 26;                         // 0..23 feats, 24..25 code
    const bool isF = v < 24;
    const int ks   = isF ? v : v - 24;
    const int g    = ks * 4 + q;                       // 8-channel group index

    const float* src0; float* nrm; short* out; int NKS;
    if (isF) {
        src0 = (set ? f1 : f0) + ((size_t)n * CF + g * 8) * HWP;
        nrm  = nrmF + (size_t)set * NPTP;
        out  = set ? OF1 : OF0;
        NKS  = 24;
    } else {
        src0 = (set ? c1in : c0in) + ((size_t)n * CC + g * 8) * HWP;
        nrm  = nrmC + (size_t)set * NPTP;
        out  = set ? OC1 : OC0;
        NKS  = 2;
    }
    const float* gr = set ? g1 : g0;
    const int t = threadIdx.x;

    __shared__ float plane[2][4096];   // 2 x 16 KB double buffer (784 f4 used)

    // ---- per-position bilinear meta, computed once ----
    int   po[7], pdx[7], pdw[7];
    float pw[7][4];
    #pragma unroll
    for (int i = 0; i < 7; i++) {
        int p = t + i * 256;
        if (p < PP) {
            float2 gg = *(const float2*)&gr[2 * (n * PP + p)];
            int o00, o01, o10, o11; float w00, w01, w10, w11;
            bilin(gg.x*2.f - 1.f, gg.y*2.f - 1.f, o00, o01, o10, o11, w00, w01, w10, w11);
            po[i] = o00; pdx[i] = o01 - o00; pdw[i] = o10 - o00;
            pw[i][0] = w00; pw[i][1] = w01; pw[i][2] = w10; pw[i][3] = w11;
        } else {
            po[i] = 0; pdx[i] = 0; pdw[i] = 0;
            pw[i][0] = pw[i][1] = pw[i][2] = pw[i][3] = 0.f;   // pad -> exact 0
        }
    }

    auto* pl3 = (__attribute__((address_space(3))) char*)&plane[0][0];

#define ISSUE(C)                                                                    \
    do {                                                                            \
        const char* sp_ = (const char*)(src0 + (C) * HWP);                          \
        _Pragma("unroll")                                                           \
        for (int i_ = 0; i_ < 4; i_++) {                                            \
            int j_  = t + i_ * 256;                                                 \
            int jc_ = min(j_, 783);                                                 \
            __builtin_amdgcn_global_load_lds((gas_p)(sp_ + jc_ * 16),               \
                (las_p)(pl3 + (((C) & 1) * 16384 + j_ * 16)), 16, 0, 0);            \
        }                                                                           \
    } while (0)

    float ss[7];
    short ov[7][8] __attribute__((aligned(16)));
    #pragma unroll
    for (int i = 0; i < 7; i++) ss[i] = 0.f;

    ISSUE(0);
    #pragma unroll
    for (int c = 0; c < 8; c++) {
        if (c < 7) {
            ISSUE(c + 1);
            asm volatile("s_waitcnt vmcnt(4)" ::: "memory");   // my ch-c loads done
        } else {
            asm volatile("s_waitcnt vmcnt(0)" ::: "memory");
        }
        __builtin_amdgcn_sched_barrier(0);
        __builtin_amdgcn_s_barrier();              // all waves' ch-c loads done
        const float* pl = &plane[c & 1][0];
        #pragma unroll
        for (int i = 0; i < 7; i++) {
            float val = pw[i][0] * pl[po[i]]
                      + pw[i][1] * pl[po[i] + pdx[i]]
                      + pw[i][2] * pl[po[i] + pdw[i]]
                      + pw[i][3] * pl[po[i] + pdw[i] + pdx[i]];
            ss[i] += val * val;
            __hip_bfloat16 b = __float2bfloat16(val);
            ov[i][c] = *(short*)&b;
        }
        __builtin_amdgcn_sched_barrier(0);
        __builtin_amdgcn_s_barrier();              // compute done before reuse
    }
#undef ISSUE

    // [n][ks][p][32] layout: base of this block's quarter (identical)
    const size_t obase = ((size_t)(n * NKS + ks)) * PPAD * 32 + q * 8;
    #pragma unroll
    for (int i = 0; i < 7; i++) {
        int p = t + i * 256;
        if (p < PPAD) {
            *(short8*)&out[obase + (size_t)p * 32] = *(const short8*)&ov[i][0];
            if (p < PP) atomicAdd(&nrm[n * PPAD + p], ss[i]);
        }
    }
}

// ---------------------------------------------------------------------------
// Kernel 2: nrm -> scale (validated round 10). Pad rows -> scale 0.
// ---------------------------------------------------------------------------
__global__ __launch_bounds__(256) void k_nrm(
    const float* __restrict__ nrmF, const float* __restrict__ nrmC,
    float* __restrict__ sclF, float* __restrict__ sclC)
{
    const int i = blockIdx.x * 256 + threadIdx.x;    // [0, 2*NPTP)
    if (i >= 2 * NPTP) return;
    const float* nrm = blockIdx.y ? nrmC : nrmF;
    float*       scl = blockIdx.y ? sclC : sclF;
    const int p = i % PPAD;
    float s = (p < PP) ? 1.f / fmaxf(sqrtf(nrm[i]), 1e-10f) : 0.f;
    scl[i] = s;
}

// ---------------------------------------------------------------------------
// Kernel 3: fused dual correlation GEMM — round 20: same proven 128x128 tile,
// 4 waves, XOR swizzle, [n][ks][p][32] staging, pcd pack, epilogue — but
// BK=64 per buffer, 2 buffers (the T3 "minimum 2-phase" template): 13 slots
// x {vmcnt+barrier, stage next 64-K slab (8 glds), 32 MFMA + 16 ds_read}
// instead of 26 barrier-coupled BK=32 slots. Halves sync overhead per FLOP;
// m230/m248 measured 655-682 TF at exactly this geometry (vs our 450).
// LDS 64KB -> 2 blocks/CU (8 waves/CU; round-3 showed waves beyond ~9 idle).
// Ledger: prologue stages cd(8)+fd0(8) -> slot0 waits vmcnt(8); in-loop each
// slot waits vmcnt(0) for the 8 loads staged one full slot (~compute64) ago.
// ---------------------------------------------------------------------------
__global__ __launch_bounds__(256, 3) void k_corr(
    const short* __restrict__ A, const short* __restrict__ B,
    const short* __restrict__ C, const short* __restrict__ D,
    const float* __restrict__ sF, const float* __restrict__ sC,
    float* __restrict__ rowfd, float* __restrict__ rowrc, float* __restrict__ t1out)
{
    // XCD-chunked swizzle: 2704 blocks = 8 XCDs x 338; x fastest within chunk
    const int flat = blockIdx.x;
    const int v   = (flat & 7) * 338 + (flat >> 3);
    const int n   = v / 169;
    const int rr  = v - n * 169;
    const int bp1 = (rr / 13) * 128;
    const int bp2 = (rr % 13) * 128;

    __shared__ short As[2][8192];   // 2 buffers x 16 KB (128 rows x 64 k)
    __shared__ short Bs[2][8192];

    const int t    = threadIdx.x;
    const int wv   = t >> 6, lane = t & 63;
    const int wm   = wv >> 1, wn = wv & 1;
    const int frow = lane & 15, fcg = lane >> 4;     // fragment row / k-chunk
    const int fslot = fcg ^ ((frow >> 1) & 3);       // bank-swizzled slot

    // staging geometry: chunk g = (wv*2+i)*64 + lane, g in [0,512) per slab
    const int sg0  = wv * 2 * 64 + lane;
    const int row0 = sg0 >> 2,        cg0 = (sg0 & 3) ^ ((row0 >> 1) & 3);
    const int sg1  = sg0 + 64;
    const int row1 = sg1 >> 2,        cg1 = (sg1 & 3) ^ ((row1 >> 1) & 3);

    const size_t kstep = (size_t)PPAD * 32;          // shorts per BK=32 slab
    const short* fdA = A + (size_t)n * 24 * kstep;
    const short* fdB = B + (size_t)n * 24 * kstep;
    const short* cdC = C + (size_t)n * 2 * kstep;
    const short* cdD = D + (size_t)n * 2 * kstep;
    const size_t toA0 = (size_t)(bp1 + row0) * 32 + cg0 * 8;
    const size_t toA1 = (size_t)(bp1 + row1) * 32 + cg1 * 8;
    const size_t toB0 = (size_t)(bp2 + row0) * 32 + cg0 * 8;
    const size_t toB1 = (size_t)(bp2 + row1) * 32 + cg1 * 8;

    auto* As3 = (__attribute__((address_space(3))) short*)&As[0][0];
    auto* Bs3 = (__attribute__((address_space(3))) short*)&Bs[0][0];
    const int ldsA0 = (wv * 2    ) * 512;  // shorts within one 4096-short slab
    const int ldsA1 = (wv * 2 + 1) * 512;

// stage one BK=64 tile (two BK=32 slabs) into buffer BUF: 8 glds/thread
#define STAGE64(PA, PB, OFF, BUF)                                                   \
    do {                                                                            \
        _Pragma("unroll")                                                           \
        for (int kk_ = 0; kk_ < 2; kk_++) {                                         \
            const size_t o_ = (OFF) + (size_t)kk_ * kstep;                          \
            const int b_ = (BUF) * 8192 + kk_ * 4096;                               \
            __builtin_amdgcn_global_load_lds((gas_p)((PA) + toA0 + o_),             \
                                             (las_p)(As3 + b_ + ldsA0), 16, 0, 0);  \
            __builtin_amdgcn_global_load_lds((gas_p)((PA) + toA1 + o_),             \
                                             (las_p)(As3 + b_ + ldsA1), 16, 0, 0);  \
            __builtin_amdgcn_global_load_lds((gas_p)((PB) + toB0 + o_),             \
                                             (las_p)(Bs3 + b_ + ldsA0), 16, 0, 0);  \
            __builtin_amdgcn_global_load_lds((gas_p)((PB) + toB1 + o_),             \
                                             (las_p)(Bs3 + b_ + ldsA1), 16, 0, 0);  \
        }                                                                           \
    } while (0)

// compute one BK=64 tile from buffer BUF: 2 x (8 ds_read_b128 + 16 MFMA)
#define COMPUTE64(BUF, ACC)                                                         \
    do {                                                                            \
        _Pragma("unroll")                                                           \
        for (int kk_ = 0; kk_ < 2; kk_++) {                                         \
            const int b_ = kk_ * 4096;                                              \
            short8 af[4], bf[4];                                                    \
            _Pragma("unroll")                                                       \
            for (int m = 0; m < 4; m++)                                             \
                af[m] = *(const short8*)&As[BUF][b_ + (wm*64 + m*16 + frow)*32 + fslot*8]; \
            _Pragma("unroll")                                                       \
            for (int q = 0; q < 4; q++)                                             \
                bf[q] = *(const short8*)&Bs[BUF][b_ + (wn*64 + q*16 + frow)*32 + fslot*8]; \
            _Pragma("unroll")                                                       \
            for (int m = 0; m < 4; m++)                                             \
                _Pragma("unroll")                                                   \
                for (int q = 0; q < 4; q++)                                         \
                    ACC[m][q] = __builtin_amdgcn_mfma_f32_16x16x32_bf16(af[m], bf[q], ACC[m][q], 0, 0, 0); \
        }                                                                           \
    } while (0)

#define WAITV8  do { asm volatile("s_waitcnt vmcnt(8)" ::: "memory");               \
                     __builtin_amdgcn_sched_barrier(0);                             \
                     __builtin_amdgcn_s_barrier(); } while (0)
#define WAITV0  do { asm volatile("s_waitcnt vmcnt(0)" ::: "memory");               \
                     __builtin_amdgcn_sched_barrier(0);                             \
                     __builtin_amdgcn_s_barrier(); } while (0)

    unsigned pcd[4][4][2];   // raw relu(cd) packed as bf16 pairs (32 VGPR)

    // ---- prologue: stage slot0 (cd, K=64) and slot1 (fd pair 0) ----
    STAGE64(cdC, cdD, 0, 0);
    STAGE64(fdA, fdB, 0, 1);

    // ---- slot 0: cd (both K-steps in buf0) ----
    {
        f32x4 acccd[4][4];
        #pragma unroll
        for (int m = 0; m < 4; m++)
            #pragma unroll
            for (int q = 0; q < 4; q++)
                #pragma unroll
                for (int r = 0; r < 4; r++) acccd[m][q][r] = 0.f;

        WAITV8;                        // cd's 8 landed (fd0's 8 stay in flight)
        COMPUTE64(0, acccd);

        // pack raw relu(cd) -> bf16 pairs (pure VALU; scales deferred)
        #pragma unroll
        for (int m = 0; m < 4; m++)
            #pragma unroll
            for (int q = 0; q < 4; q++) {
                float r0 = fmaxf(acccd[m][q][0], 0.f);
                float r1 = fmaxf(acccd[m][q][1], 0.f);
                float r2 = fmaxf(acccd[m][q][2], 0.f);
                float r3 = fmaxf(acccd[m][q][3], 0.f);
                pcd[m][q][0] = f2b(r0) | (f2b(r1) << 16);
                pcd[m][q][1] = f2b(r2) | (f2b(r3) << 16);
            }
    }   // acccd dies (AGPRs freed before accfd)

    // ---- slots 1..12: fd pairs 0..11 (K=64 each), buf s%2 ----
    f32x4 accfd[4][4];
    #pragma unroll
    for (int m = 0; m < 4; m++)
        #pragma unroll
        for (int q = 0; q < 4; q++)
            #pragma unroll
            for (int r = 0; r < 4; r++) accfd[m][q][r] = 0.f;

    for (int kp = 0; kp < 6; kp++) {
        const size_t tb = (size_t)(4 * kp) * kstep;   // fd K-step base
        // slot 2kp+1: compute fd pair 2kp (buf1), stage pair 2kp+1 -> buf0
        WAITV0;
        STAGE64(fdA, fdB, tb + 2 * kstep, 0);
        COMPUTE64(1, accfd);
        // slot 2kp+2: compute fd pair 2kp+1 (buf0), stage pair 2kp+2 -> buf1
        WAITV0;
        if (kp < 5) STAGE64(fdA, fdB, tb + 4 * kstep, 1);
        COMPUTE64(0, accfd);
    }
#undef STAGE64
#undef COMPUTE64
#undef WAITV8
#undef WAITV0

    // ---- single deferred epilogue: scales + t1 + rowfd + rowrc ----
    // C/D layout: col = lane&15, row = (lane>>4)*4 + reg
    float scc_[4], sfc_[4];
    #pragma unroll
    for (int q = 0; q < 4; q++) {
        size_t colp = (size_t)NPTP + (size_t)n * PPAD + bp2 + wn*64 + q*16 + frow;
        scc_[q] = sC[colp];
        sfc_[q] = sF[colp];
    }

    float t1 = 0.f;
    #pragma unroll
    for (int m = 0; m < 4; m++) {
        #pragma unroll
        for (int r = 0; r < 4; r++) {
            size_t rowp = (size_t)n * PPAD + bp1 + wm*64 + m*16 + fcg*4 + r;
            float scr = sC[rowp];
            float sfr = sF[rowp];
            float sf = 0.f, sr = 0.f;
            #pragma unroll
            for (int q = 0; q < 4; q++) {
                float fdv = accfd[m][q][r] * sfr * sfc_[q];
                float rcv = bup(pcd[m][q][r >> 1], r & 1) * scr * scc_[q];
                t1 += rcv * fdv;
                sf += fdv;
                sr += rcv;
            }
            #pragma unroll
            for (int d = 1; d < 16; d <<= 1) {
                sf += __shfl_xor(sf, d, 64);
                sr += __shfl_xor(sr, d, 64);
            }
            if ((lane & 15) == 0) {
                int row = bp1 + wm*64 + m*16 + fcg*4 + r;
                atomicAdd(&rowfd[n * PPAD + row], sf);
                atomicAdd(&rowrc[n * PPAD + row], sr);
            }
        }
    }
    #pragma unroll
    for (int d = 1; d < 64; d <<= 1) t1 += __shfl_xor(t1, d, 64);
    __shared__ float t1s[4];
    if (lane == 0) t1s[wv] = t1;
    __syncthreads();
    if (t == 0) atomicAdd(t1out, t1s[0] + t1s[1] + t1s[2] + t1s[3]);
}

// ---------------------------------------------------------------------------
// Kernel 4: finalize. loss = -(T1 - cross/PP + (Sfd/M)*Src)/M
// ---------------------------------------------------------------------------
__global__ __launch_bounds__(1024) void k_final(
    const float* __restrict__ rowfd, const float* __restrict__ rowrc,
    const float* __restrict__ t1p, float* __restrict__ out)
{
    const int t = threadIdx.x;
    double cr = 0.0, sf = 0.0, sr = 0.0;
    for (int i = t; i < NN * PPAD; i += 1024) {
        double a = rowfd[i], b = rowrc[i];
        cr += a * b; sf += a; sr += b;
    }
    __shared__ double sh[1024];
    sh[t] = cr; __syncthreads();
    for (int s = 512; s > 0; s >>= 1) { if (t < s) sh[t] += sh[t + s]; __syncthreads(); }
    cr = sh[0]; __syncthreads();
    sh[t] = sf; __syncthreads();
    for (int s = 512; s > 0; s >>= 1) { if (t < s) sh[t] += sh[t + s]; __syncthreads(); }
    sf = sh[0]; __syncthreads();
    sh[t] = sr; __syncthreads();
    for (int s = 512; s > 0; s >>= 1) { if (t < s) sh[t] += sh[t + s]; __syncthreads(); }
    sr = sh[0];
    if (t == 0) {
        double M = (double)NN * (double)PP * (double)PP;
        double t1 = (double)t1p[0];
        double bracket = t1 - cr / (double)PP + (sf / M) * sr;
        out[0] = (float)(-bracket / M);
    }
}

// ---------------------------------------------------------------------------
extern "C" void kernel_launch(void* const* d_in, const int* in_sizes, int n_in,
                              void* d_out, int out_size, void* d_ws, size_t ws_size,
                              hipStream_t stream)
{
    const float* orig_feats     = (const float*)d_in[0];
    const float* orig_feats_pos = (const float*)d_in[1];
    const float* orig_code      = (const float*)d_in[2];
    const float* orig_code_pos  = (const float*)d_in[3];
    const float* coords1        = (const float*)d_in[4];
    const float* coords2        = (const float*)d_in[5];

    // ---- workspace layout (total 89,669,888 B) ----
    char* ws = (char*)d_ws;
    float* t1    = (float*)(ws + 0);                      //      256 B
    float* rowfd = (float*)(ws + 256);                    //  106,496 B (NN*PPAD)
    float* rowrc = (float*)(ws + 106752);                 //  106,496 B
    float* nrmF  = (float*)(ws + 213248);                 //  212,992 B (2*NPTP)
    float* nrmC  = (float*)(ws + 426240);                 //  212,992 B
    const size_t zeroBytes = 639232;                      // t1+rowsums+nrms
    float* sclF  = (float*)(ws + 639232);                 //  212,992 B
    float* sclC  = (float*)(ws + 852224);                 //  212,992 B
    short* OF0 = (short*)(ws + 1065216);                  // [16][24][1664][32] bf16
    short* OF1 = (short*)(ws + 1065216 + 40894464ull);
    short* OC0 = (short*)(ws + 1065216 + 2*40894464ull);  // [16][2][1664][32] bf16
    short* OC1 = (short*)(ws + 1065216 + 2*40894464ull + 3407872ull);

    (void)hipMemsetAsync(d_ws, 0, zeroBytes, stream);   // t1/rowsums/nrms

    k_sample<<<dim3(3328), 256, 0, stream>>>(
        orig_feats, orig_feats_pos, orig_code, orig_code_pos,
        coords1, coords2, nrmF, nrmC, OF0, OF1, OC0, OC1);

    k_nrm<<<dim3((2*NPTP + 255)/256, 2), 256, 0, stream>>>(
        nrmF, nrmC, sclF, sclC);

    k_corr<<<dim3(2704), 256, 0, stream>>>(
        OF0, OF1, OC0, OC1, sclF, sclC, rowfd, rowrc, t1);

    k_final<<<1, 1024, 0, stream>>>(rowfd, rowrc, t1, (float*)d_out);
}

// Round 7
// 242.127 us; speedup vs baseline: 1.0893x; 1.0893x over previous
//
#include <hip/hip_runtime.h>
#include <hip/hip_bf16.h>

// Problem constants
#define NN 16
#define CF 768
#define CC 64
#define HH 56
#define WW 56
#define SS 40
#define PP (SS*SS)          // 1600 positions per image
#define PPAD 1664           // padded to 13*128 for 128-tile GEMM
#define NPT (NN*PP)         // 25600
#define NPTP (NN*PPAD)      // 26624
#define HWP (HH*WW)         // 3136

typedef __attribute__((ext_vector_type(8))) short short8;
typedef __attribute__((ext_vector_type(4))) float f32x4;

typedef const __attribute__((address_space(1))) void* gas_p;
typedef __attribute__((address_space(3))) void* las_p;

__device__ __forceinline__ unsigned f2b(float f) {
    __hip_bfloat16 b = __float2bfloat16(f);
    return (unsigned)*(unsigned short*)&b;
}
__device__ __forceinline__ float bup(unsigned u, int hi) {
    unsigned bits = hi ? (u & 0xffff0000u) : (u << 16);
    return __uint_as_float(bits);
}

// Shared bilinear helper — EXACT same arithmetic as validated round-1 kernel.
__device__ __forceinline__ void bilin(float gx, float gy,
    int& o00, int& o01, int& o10, int& o11,
    float& w00, float& w01, float& w10, float& w11)
{
    float x = (gx + 1.f) * 0.5f * (float)(WW - 1);
    float y = (gy + 1.f) * 0.5f * (float)(HH - 1);
    x = fminf(fmaxf(x, 0.f), (float)(WW - 1));
    y = fminf(fmaxf(y, 0.f), (float)(HH - 1));
    float xf = floorf(x), yf = floorf(y);
    int x0 = (int)xf, y0 = (int)yf;
    int x1 = min(x0 + 1, WW - 1), y1 = min(y0 + 1, HH - 1);
    float wx = x - xf, wy = y - yf;
    w00 = (1.f-wx)*(1.f-wy); w01 = wx*(1.f-wy); w10 = (1.f-wx)*wy; w11 = wx*wy;
    o00 = y0*WW + x0; o01 = y0*WW + x1; o10 = y1*WW + x0; o11 = y1*WW + x1;
}

// ---------------------------------------------------------------------------
// Kernel 1: sampling — round-4 validated pipeline (2x16KB dbuf plane,
// global_load_lds, vmcnt(4), meta-once). Round 22: FEATS outputs packed fp8
// e4m3 (v_cvt_pk_fp8_f32 with LITERAL sel args — round-6 compile fix) into
// [n][24][1664][32B]; CODE outputs stay bf16 [n][2][1664][32 shorts].
// Channel values buffered in fv[7][8] (all indices compile-time constants).
// ---------------------------------------------------------------------------
__global__ __launch_bounds__(256) void k_sample(
    const float* __restrict__ f0, const float* __restrict__ f1,
    const float* __restrict__ c0in, const float* __restrict__ c1in,
    const float* __restrict__ g0, const float* __restrict__ g1,
    float* __restrict__ nrmF, float* __restrict__ nrmC,
    unsigned char* __restrict__ OF0, unsigned char* __restrict__ OF1,
    short* __restrict__ OC0, short* __restrict__ OC1)
{
    // decode quarter-interleaved flat index (identical to validated kernel)
    const int flat = blockIdx.x;                       // [0, 3328)
    const int q    = (flat >> 3) & 3;                  // quarter
    const int u    = ((flat >> 5) << 3) | (flat & 7);  // [0, 832)
    const int set  = u / 416;                          // 26*16 = 416
    const int rem  = u % 416;
    const int n    = rem / 26;
    const int v    = rem % 26;                         // 0..23 feats, 24..25 code
    const bool isF = v < 24;
    const int ks   = isF ? v : v - 24;
    const int g    = ks * 4 + q;                       // 8-channel group index

    const float* src0; float* nrm;
    if (isF) {
        src0 = (set ? f1 : f0) + ((size_t)n * CF + g * 8) * HWP;
        nrm  = nrmF + (size_t)set * NPTP;
    } else {
        src0 = (set ? c1in : c0in) + ((size_t)n * CC + g * 8) * HWP;
        nrm  = nrmC + (size_t)set * NPTP;
    }
    unsigned char* outF = set ? OF1 : OF0;
    short*         outC = set ? OC1 : OC0;
    const float* gr = set ? g1 : g0;
    const int t = threadIdx.x;

    __shared__ float plane[2][4096];   // 2 x 16 KB double buffer (784 f4 used)

    // ---- per-position bilinear meta, computed once ----
    int   po[7], pdx[7], pdw[7];
    float pw[7][4];
    #pragma unroll
    for (int i = 0; i < 7; i++) {
        int p = t + i * 256;
        if (p < PP) {
            float2 gg = *(const float2*)&gr[2 * (n * PP + p)];
            int o00, o01, o10, o11; float w00, w01, w10, w11;
            bilin(gg.x*2.f - 1.f, gg.y*2.f - 1.f, o00, o01, o10, o11, w00, w01, w10, w11);
            po[i] = o00; pdx[i] = o01 - o00; pdw[i] = o10 - o00;
            pw[i][0] = w00; pw[i][1] = w01; pw[i][2] = w10; pw[i][3] = w11;
        } else {
            po[i] = 0; pdx[i] = 0; pdw[i] = 0;
            pw[i][0] = pw[i][1] = pw[i][2] = pw[i][3] = 0.f;   // pad -> exact 0
        }
    }

    auto* pl3 = (__attribute__((address_space(3))) char*)&plane[0][0];

#define ISSUE(C)                                                                    \
    do {                                                                            \
        const char* sp_ = (const char*)(src0 + (C) * HWP);                          \
        _Pragma("unroll")                                                           \
        for (int i_ = 0; i_ < 4; i_++) {                                            \
            int j_  = t + i_ * 256;                                                 \
            int jc_ = min(j_, 783);                                                 \
            __builtin_amdgcn_global_load_lds((gas_p)(sp_ + jc_ * 16),               \
                (las_p)(pl3 + (((C) & 1) * 16384 + j_ * 16)), 16, 0, 0);            \
        }                                                                           \
    } while (0)

    float ss[7];
    float fv[7][8];     // per-position channel values (indices all constant)
    #pragma unroll
    for (int i = 0; i < 7; i++) ss[i] = 0.f;

    ISSUE(0);
    #pragma unroll
    for (int c = 0; c < 8; c++) {
        if (c < 7) {
            ISSUE(c + 1);
            asm volatile("s_waitcnt vmcnt(4)" ::: "memory");   // my ch-c loads done
        } else {
            asm volatile("s_waitcnt vmcnt(0)" ::: "memory");
        }
        __builtin_amdgcn_sched_barrier(0);
        __builtin_amdgcn_s_barrier();              // all waves' ch-c loads done
        const float* pl = &plane[c & 1][0];
        #pragma unroll
        for (int i = 0; i < 7; i++) {
            float val = pw[i][0] * pl[po[i]]
                      + pw[i][1] * pl[po[i] + pdx[i]]
                      + pw[i][2] * pl[po[i] + pdw[i]]
                      + pw[i][3] * pl[po[i] + pdw[i] + pdx[i]];
            ss[i] += val * val;
            fv[i][c] = val;
        }
        __builtin_amdgcn_sched_barrier(0);
        __builtin_amdgcn_s_barrier();              // compute done before reuse
    }
#undef ISSUE

    if (isF) {
        // [n][24][p][32 B] fp8 layout; this block's quarter at byte q*8
        const size_t ob = ((size_t)(n * 24 + ks)) * PPAD * 32 + q * 8;
        #pragma unroll
        for (int i = 0; i < 7; i++) {
            int p = t + i * 256;
            if (p < PPAD) {
                unsigned w0 = 0u, w1 = 0u;
                w0 = __builtin_amdgcn_cvt_pk_fp8_f32(fv[i][0], fv[i][1], w0, 0);
                w0 = __builtin_amdgcn_cvt_pk_fp8_f32(fv[i][2], fv[i][3], w0, 1);
                w1 = __builtin_amdgcn_cvt_pk_fp8_f32(fv[i][4], fv[i][5], w1, 0);
                w1 = __builtin_amdgcn_cvt_pk_fp8_f32(fv[i][6], fv[i][7], w1, 1);
                uint2 w; w.x = w0; w.y = w1;
                *(uint2*)&outF[ob + (size_t)p * 32] = w;
                if (p < PP) atomicAdd(&nrm[n * PPAD + p], ss[i]);
            }
        }
    } else {
        // [n][2][p][32 shorts] bf16 layout (unchanged)
        const size_t ob = ((size_t)(n * 2 + ks)) * PPAD * 32 + q * 8;
        #pragma unroll
        for (int i = 0; i < 7; i++) {
            int p = t + i * 256;
            if (p < PPAD) {
                short ov[8] __attribute__((aligned(16)));
                #pragma unroll
                for (int c = 0; c < 8; c++) {
                    __hip_bfloat16 b = __float2bfloat16(fv[i][c]);
                    ov[c] = *(short*)&b;
                }
                *(short8*)&outC[ob + (size_t)p * 32] = *(const short8*)ov;
                if (p < PP) atomicAdd(&nrm[n * PPAD + p], ss[i]);
            }
        }
    }
}

// ---------------------------------------------------------------------------
// Kernel 2: nrm -> scale (validated round 10). Pad rows -> scale 0.
// ---------------------------------------------------------------------------
__global__ __launch_bounds__(256) void k_nrm(
    const float* __restrict__ nrmF, const float* __restrict__ nrmC,
    float* __restrict__ sclF, float* __restrict__ sclC)
{
    const int i = blockIdx.x * 256 + threadIdx.x;    // [0, 2*NPTP)
    if (i >= 2 * NPTP) return;
    const float* nrm = blockIdx.y ? nrmC : nrmF;
    float*       scl = blockIdx.y ? sclC : sclF;
    const int p = i % PPAD;
    float s = (p < PP) ? 1.f / fmaxf(sqrtf(nrm[i]), 1e-10f) : 0.f;
    scl[i] = s;
}

// ---------------------------------------------------------------------------
// Kernel 3: fused dual correlation GEMM — round 22: r15's proven 3-buffer
// counted-vmcnt 26-slot schedule, with fd operands in FP8 e4m3 (staged bytes
// per slot halve: 4KB vs 8KB/slab -> attacks the measured ~6.8 TB/s L2/L3
// staging-BW wall). cd slots stay bf16 (validated path, swizzled reads).
// fd LDS rows are 32 B read by ds_read_b64: 64 lanes x 8B = 4 accesses/bank
// (the minimum) -> no swizzle needed. MFMA count unchanged (fp8 16x16x32
// has the same K=32); this is purely a bandwidth play.
// ---------------------------------------------------------------------------
__global__ __launch_bounds__(256, 3) void k_corr(
    const unsigned char* __restrict__ A, const unsigned char* __restrict__ B,
    const short* __restrict__ C, const short* __restrict__ D,
    const float* __restrict__ sF, const float* __restrict__ sC,
    float* __restrict__ rowfd, float* __restrict__ rowrc, float* __restrict__ t1out)
{
    // XCD-chunked swizzle: 2704 blocks = 8 XCDs x 338; x fastest within chunk
    const int flat = blockIdx.x;
    const int v   = (flat & 7) * 338 + (flat >> 3);
    const int n   = v / 169;
    const int rr  = v - n * 169;
    const int bp1 = (rr / 13) * 128;
    const int bp2 = (rr % 13) * 128;

    __shared__ char Asb[3][8192];   // 3 buffers x 8 KB (cd bf16 slab / fd fp8 slab)
    __shared__ char Bsb[3][8192];

    const int t    = threadIdx.x;
    const int wv   = t >> 6, lane = t & 63;
    const int wm   = wv >> 1, wn = wv & 1;
    const int frow = lane & 15, fcg = lane >> 4;     // fragment row / k-chunk
    const int fslot = fcg ^ ((frow >> 1) & 3);       // bank-swizzled slot (cd bf16)

    // ---- cd (bf16) staging geometry: chunk g = (wv*2+i)*64 + lane, [0,512)
    const int sg0  = wv * 2 * 64 + lane;
    const int row0 = sg0 >> 2,        cg0 = (sg0 & 3) ^ ((row0 >> 1) & 3);
    const int sg1  = sg0 + 64;
    const int row1 = sg1 >> 2,        cg1 = (sg1 & 3) ^ ((row1 >> 1) & 3);
    const size_t kstep_s = (size_t)PPAD * 32;        // shorts per bf16 BK=32 slab
    const short* cdC = C + (size_t)n * 2 * kstep_s;
    const short* cdD = D + (size_t)n * 2 * kstep_s;
    const size_t toA0 = (size_t)(bp1 + row0) * 32 + cg0 * 8;
    const size_t toA1 = (size_t)(bp1 + row1) * 32 + cg1 * 8;
    const size_t toB0 = (size_t)(bp2 + row0) * 32 + cg0 * 8;
    const size_t toB1 = (size_t)(bp2 + row1) * 32 + cg1 * 8;
    auto* As3s = (__attribute__((address_space(3))) short*)&Asb[0][0];
    auto* Bs3s = (__attribute__((address_space(3))) short*)&Bsb[0][0];
    const short* AsS = (const short*)&Asb[0][0];
    const short* BsS = (const short*)&Bsb[0][0];
    const int ldsA0 = (wv * 2    ) * 512;  // shorts within one 4096-short buffer
    const int ldsA1 = (wv * 2 + 1) * 512;

    // ---- fd (fp8) staging geometry: slab = [128 rows][32 B] = 4 KB, 256 chunks
    const size_t FDSTEP = (size_t)PPAD * 32;         // BYTES per fp8 BK=32 slab
    const unsigned char* fdA = A + (size_t)n * 24 * FDSTEP;
    const unsigned char* fdB = B + (size_t)n * 24 * FDSTEP;
    const size_t toAf = (size_t)(bp1 + (t >> 1)) * 32 + (t & 1) * 16;
    const size_t toBf = (size_t)(bp2 + (t >> 1)) * 32 + (t & 1) * 16;
    auto* Asb3 = (__attribute__((address_space(3))) char*)&Asb[0][0];
    auto* Bsb3 = (__attribute__((address_space(3))) char*)&Bsb[0][0];
    const int fldsW = wv * 1024;                     // wave-uniform byte base

#define STAGECD(BUF, OFF)                                                           \
    do {                                                                            \
        const size_t off_ = (OFF);                                                  \
        const int b_ = (BUF) * 4096;                                                \
        __builtin_amdgcn_global_load_lds((gas_p)(cdC + toA0 + off_),                \
                                         (las_p)(As3s + b_ + ldsA0), 16, 0, 0);     \
        __builtin_amdgcn_global_load_lds((gas_p)(cdC + toA1 + off_),                \
                                         (las_p)(As3s + b_ + ldsA1), 16, 0, 0);     \
        __builtin_amdgcn_global_load_lds((gas_p)(cdD + toB0 + off_),                \
                                         (las_p)(Bs3s + b_ + ldsA0), 16, 0, 0);     \
        __builtin_amdgcn_global_load_lds((gas_p)(cdD + toB1 + off_),                \
                                         (las_p)(Bs3s + b_ + ldsA1), 16, 0, 0);     \
    } while (0)

#define STAGEF(OFF, BUF)                                                            \
    do {                                                                            \
        const size_t off_ = (OFF);                                                  \
        __builtin_amdgcn_global_load_lds((gas_p)(fdA + toAf + off_),                \
                                         (las_p)(Asb3 + (BUF) * 8192 + fldsW), 16, 0, 0); \
        __builtin_amdgcn_global_load_lds((gas_p)(fdB + toBf + off_),                \
                                         (las_p)(Bsb3 + (BUF) * 8192 + fldsW), 16, 0, 0); \
    } while (0)

#define COMPUTECD(BUF, ACC)                                                         \
    do {                                                                            \
        short8 af[4], bf[4];                                                        \
        _Pragma("unroll")                                                           \
        for (int m = 0; m < 4; m++)                                                 \
            af[m] = *(const short8*)&AsS[(BUF)*4096 + (wm*64 + m*16 + frow)*32 + fslot*8]; \
        _Pragma("unroll")                                                           \
        for (int q = 0; q < 4; q++)                                                 \
            bf[q] = *(const short8*)&BsS[(BUF)*4096 + (wn*64 + q*16 + frow)*32 + fslot*8]; \
        _Pragma("unroll")                                                           \
        for (int m = 0; m < 4; m++)                                                 \
            _Pragma("unroll")                                                       \
            for (int q = 0; q < 4; q++)                                             \
                ACC[m][q] = __builtin_amdgcn_mfma_f32_16x16x32_bf16(af[m], bf[q], ACC[m][q], 0, 0, 0); \
    } while (0)

#define COMPUTEF(BUF, ACC)                                                          \
    do {                                                                            \
        long af[4], bf[4];                                                          \
        _Pragma("unroll")                                                           \
        for (int m = 0; m < 4; m++)                                                 \
            af[m] = *(const long*)&Asb[BUF][(wm*64 + m*16 + frow)*32 + fcg*8];      \
        _Pragma("unroll")                                                           \
        for (int q = 0; q < 4; q++)                                                 \
            bf[q] = *(const long*)&Bsb[BUF][(wn*64 + q*16 + frow)*32 + fcg*8];      \
        _Pragma("unroll")                                                           \
        for (int m = 0; m < 4; m++)                                                 \
            _Pragma("unroll")                                                       \
            for (int q = 0; q < 4; q++)                                             \
                ACC[m][q] = __builtin_amdgcn_mfma_f32_16x16x32_fp8_fp8(af[m], bf[q], ACC[m][q], 0, 0, 0); \
    } while (0)

#define WAITV4  do { asm volatile("s_waitcnt vmcnt(4)" ::: "memory");               \
                     __builtin_amdgcn_sched_barrier(0);                             \
                     __builtin_amdgcn_s_barrier(); } while (0)
#define WAITV2  do { asm volatile("s_waitcnt vmcnt(2)" ::: "memory");               \
                     __builtin_amdgcn_sched_barrier(0);                             \
                     __builtin_amdgcn_s_barrier(); } while (0)
#define WAITV0  do { asm volatile("s_waitcnt vmcnt(0)" ::: "memory");               \
                     __builtin_amdgcn_sched_barrier(0);                             \
                     __builtin_amdgcn_s_barrier(); } while (0)

    unsigned pcd[4][4][2];   // raw relu(cd) packed as bf16 pairs (32 VGPR)

    // ---- prologue: stage cd steps 0,1 (4 glds each) ----
    STAGECD(0, 0);
    STAGECD(1, kstep_s);

    // ---- cd slots 0,1 ----
    {
        f32x4 acccd[4][4];
        #pragma unroll
        for (int m = 0; m < 4; m++)
            #pragma unroll
            for (int q = 0; q < 4; q++)
                #pragma unroll
                for (int r = 0; r < 4; r++) acccd[m][q][r] = 0.f;

        WAITV4;                         // cd0 landed (cd1's 4 in flight)
        STAGEF(0, 2);                   // fd step 0 -> buf2 (+2)
        COMPUTECD(0, acccd);
        WAITV2;                         // cd1 landed (fd0's 2 in flight)
        STAGEF(1 * FDSTEP, 0);          // fd step 1 -> buf0 (+2)
        COMPUTECD(1, acccd);

        // pack raw relu(cd) -> bf16 pairs (pure VALU; scales deferred)
        #pragma unroll
        for (int m = 0; m < 4; m++)
            #pragma unroll
            for (int q = 0; q < 4; q++) {
                float r0 = fmaxf(acccd[m][q][0], 0.f);
                float r1 = fmaxf(acccd[m][q][1], 0.f);
                float r2 = fmaxf(acccd[m][q][2], 0.f);
                float r3 = fmaxf(acccd[m][q][3], 0.f);
                pcd[m][q][0] = f2b(r0) | (f2b(r1) << 16);
                pcd[m][q][1] = f2b(r2) | (f2b(r3) << 16);
            }
    }   // acccd dies (AGPRs freed before accfd)

    // ---- fd slots: 24 steps, step j in buf (2+j)%3, stage 2-ahead ----
    f32x4 accfd[4][4];
    #pragma unroll
    for (int m = 0; m < 4; m++)
        #pragma unroll
        for (int q = 0; q < 4; q++)
            #pragma unroll
            for (int r = 0; r < 4; r++) accfd[m][q][r] = 0.f;

    for (int kp = 0; kp < 8; kp++) {
        const size_t tb = (size_t)(3 * kp) * FDSTEP;
        // slot: compute fd 3kp (buf2), stage fd 3kp+2 -> buf1
        WAITV2;
        STAGEF(tb + 2 * FDSTEP, 1);
        COMPUTEF(2, accfd);
        // slot: compute fd 3kp+1 (buf0), stage fd 3kp+3 -> buf2
        WAITV2;
        if (kp < 7) STAGEF(tb + 3 * FDSTEP, 2);
        COMPUTEF(0, accfd);
        // slot: compute fd 3kp+2 (buf1), stage fd 3kp+4 -> buf0
        if (kp < 7) {
            WAITV2;
            STAGEF(tb + 4 * FDSTEP, 0);
        } else {
            WAITV0;
        }
        COMPUTEF(1, accfd);
    }
#undef STAGECD
#undef STAGEF
#undef COMPUTECD
#undef COMPUTEF
#undef WAITV4
#undef WAITV2
#undef WAITV0

    // ---- single deferred epilogue: scales + t1 + rowfd + rowrc ----
    // C/D layout: col = lane&15, row = (lane>>4)*4 + reg (dtype-independent)
    float scc_[4], sfc_[4];
    #pragma unroll
    for (int q = 0; q < 4; q++) {
        size_t colp = (size_t)NPTP + (size_t)n * PPAD + bp2 + wn*64 + q*16 + frow;
        scc_[q] = sC[colp];
        sfc_[q] = sF[colp];
    }

    float t1 = 0.f;
    #pragma unroll
    for (int m = 0; m < 4; m++) {
        #pragma unroll
        for (int r = 0; r < 4; r++) {
            size_t rowp = (size_t)n * PPAD + bp1 + wm*64 + m*16 + fcg*4 + r;
            float scr = sC[rowp];
            float sfr = sF[rowp];
            float sf = 0.f, sr = 0.f;
            #pragma unroll
            for (int q = 0; q < 4; q++) {
                float fdv = accfd[m][q][r] * sfr * sfc_[q];
                float rcv = bup(pcd[m][q][r >> 1], r & 1) * scr * scc_[q];
                t1 += rcv * fdv;
                sf += fdv;
                sr += rcv;
            }
            #pragma unroll
            for (int d = 1; d < 16; d <<= 1) {
                sf += __shfl_xor(sf, d, 64);
                sr += __shfl_xor(sr, d, 64);
            }
            if ((lane & 15) == 0) {
                int row = bp1 + wm*64 + m*16 + fcg*4 + r;
                atomicAdd(&rowfd[n * PPAD + row], sf);
                atomicAdd(&rowrc[n * PPAD + row], sr);
            }
        }
    }
    #pragma unroll
    for (int d = 1; d < 64; d <<= 1) t1 += __shfl_xor(t1, d, 64);
    __shared__ float t1s[4];
    if (lane == 0) t1s[wv] = t1;
    __syncthreads();
    if (t == 0) atomicAdd(t1out, t1s[0] + t1s[1] + t1s[2] + t1s[3]);
}

// ---------------------------------------------------------------------------
// Kernel 4: finalize. loss = -(T1 - cross/PP + (Sfd/M)*Src)/M
// ---------------------------------------------------------------------------
__global__ __launch_bounds__(1024) void k_final(
    const float* __restrict__ rowfd, const float* __restrict__ rowrc,
    const float* __restrict__ t1p, float* __restrict__ out)
{
    const int t = threadIdx.x;
    double cr = 0.0, sf = 0.0, sr = 0.0;
    for (int i = t; i < NN * PPAD; i += 1024) {
        double a = rowfd[i], b = rowrc[i];
        cr += a * b; sf += a; sr += b;
    }
    __shared__ double sh[1024];
    sh[t] = cr; __syncthreads();
    for (int s = 512; s > 0; s >>= 1) { if (t < s) sh[t] += sh[t + s]; __syncthreads(); }
    cr = sh[0]; __syncthreads();
    sh[t] = sf; __syncthreads();
    for (int s = 512; s > 0; s >>= 1) { if (t < s) sh[t] += sh[t + s]; __syncthreads(); }
    sf = sh[0]; __syncthreads();
    sh[t] = sr; __syncthreads();
    for (int s = 512; s > 0; s >>= 1) { if (t < s) sh[t] += sh[t + s]; __syncthreads(); }
    sr = sh[0];
    if (t == 0) {
        double M = (double)NN * (double)PP * (double)PP;
        double t1 = (double)t1p[0];
        double bracket = t1 - cr / (double)PP + (sf / M) * sr;
        out[0] = (float)(-bracket / M);
    }
}

// ---------------------------------------------------------------------------
extern "C" void kernel_launch(void* const* d_in, const int* in_sizes, int n_in,
                              void* d_out, int out_size, void* d_ws, size_t ws_size,
                              hipStream_t stream)
{
    const float* orig_feats     = (const float*)d_in[0];
    const float* orig_feats_pos = (const float*)d_in[1];
    const float* orig_code      = (const float*)d_in[2];
    const float* orig_code_pos  = (const float*)d_in[3];
    const float* coords1        = (const float*)d_in[4];
    const float* coords2        = (const float*)d_in[5];

    // ---- workspace layout ----
    char* ws = (char*)d_ws;
    float* t1    = (float*)(ws + 0);                      //      256 B
    float* rowfd = (float*)(ws + 256);                    //  106,496 B (NN*PPAD)
    float* rowrc = (float*)(ws + 106752);                 //  106,496 B
    float* nrmF  = (float*)(ws + 213248);                 //  212,992 B (2*NPTP)
    float* nrmC  = (float*)(ws + 426240);                 //  212,992 B
    const size_t zeroBytes = 639232;                      // t1+rowsums+nrms
    float* sclF  = (float*)(ws + 639232);                 //  212,992 B
    float* sclC  = (float*)(ws + 852224);                 //  212,992 B
    unsigned char* OF0 = (unsigned char*)(ws + 1065216);  // [16][24][1664][32 B] fp8
    unsigned char* OF1 = (unsigned char*)(ws + 1065216 + 20447232ull);
    short* OC0 = (short*)(ws + 1065216 + 2*20447232ull);  // [16][2][1664][32] bf16
    short* OC1 = (short*)(ws + 1065216 + 2*20447232ull + 3407872ull);

    (void)hipMemsetAsync(d_ws, 0, zeroBytes, stream);   // t1/rowsums/nrms

    k_sample<<<dim3(3328), 256, 0, stream>>>(
        orig_feats, orig_feats_pos, orig_code, orig_code_pos,
        coords1, coords2, nrmF, nrmC, OF0, OF1, OC0, OC1);

    k_nrm<<<dim3((2*NPTP + 255)/256, 2), 256, 0, stream>>>(
        nrmF, nrmC, sclF, sclC);

    k_corr<<<dim3(2704), 256, 0, stream>>>(
        OF0, OF1, OC0, OC1, sclF, sclC, rowfd, rowrc, t1);

    k_final<<<1, 1024, 0, stream>>>(rowfd, rowrc, t1, (float*)d_out);
}

// Round 8
// 217.664 us; speedup vs baseline: 1.2117x; 1.1124x over previous
//
#include <hip/hip_runtime.h>
#include <hip/hip_bf16.h>

// Problem constants
#define NN 16
#define CF 768
#define CC 64
#define HH 56
#define WW 56
#define SS 40
#define PP (SS*SS)          // 1600 positions per image
#define PPAD 1664           // padded to 13*128 for 128-tile GEMM
#define NPT (NN*PP)         // 25600
#define NPTP (NN*PPAD)      // 26624
#define HWP (HH*WW)         // 3136

typedef __attribute__((ext_vector_type(8))) short short8;
typedef __attribute__((ext_vector_type(4))) float f32x4;

typedef const __attribute__((address_space(1))) void* gas_p;
typedef __attribute__((address_space(3))) void* las_p;

__device__ __forceinline__ unsigned f2b(float f) {
    __hip_bfloat16 b = __float2bfloat16(f);
    return (unsigned)*(unsigned short*)&b;
}
__device__ __forceinline__ float bup(unsigned u, int hi) {
    unsigned bits = hi ? (u & 0xffff0000u) : (u << 16);
    return __uint_as_float(bits);
}

// Shared bilinear helper — EXACT same arithmetic as validated round-1 kernel.
__device__ __forceinline__ void bilin(float gx, float gy,
    int& o00, int& o01, int& o10, int& o11,
    float& w00, float& w01, float& w10, float& w11)
{
    float x = (gx + 1.f) * 0.5f * (float)(WW - 1);
    float y = (gy + 1.f) * 0.5f * (float)(HH - 1);
    x = fminf(fmaxf(x, 0.f), (float)(WW - 1));
    y = fminf(fmaxf(y, 0.f), (float)(HH - 1));
    float xf = floorf(x), yf = floorf(y);
    int x0 = (int)xf, y0 = (int)yf;
    int x1 = min(x0 + 1, WW - 1), y1 = min(y0 + 1, HH - 1);
    float wx = x - xf, wy = y - yf;
    w00 = (1.f-wx)*(1.f-wy); w01 = wx*(1.f-wy); w10 = (1.f-wx)*wy; w11 = wx*wy;
    o00 = y0*WW + x0; o01 = y0*WW + x1; o10 = y1*WW + x0; o11 = y1*WW + x1;
}

// ---------------------------------------------------------------------------
// Kernel 1: sampling — round-7 validated pipeline. Round 23 change: fp8
// FEATS output layout is k-major [n][24][kchunk=4][1664][8B] (one uint2 per
// position) so k_corr can stage it transposed into LDS without conflicts.
// CODE outputs stay bf16 [n][2][1664][32 shorts] (validated path).
// ---------------------------------------------------------------------------
__global__ __launch_bounds__(256) void k_sample(
    const float* __restrict__ f0, const float* __restrict__ f1,
    const float* __restrict__ c0in, const float* __restrict__ c1in,
    const float* __restrict__ g0, const float* __restrict__ g1,
    float* __restrict__ nrmF, float* __restrict__ nrmC,
    unsigned char* __restrict__ OF0, unsigned char* __restrict__ OF1,
    short* __restrict__ OC0, short* __restrict__ OC1)
{
    // decode quarter-interleaved flat index (identical to validated kernel)
    const int flat = blockIdx.x;                       // [0, 3328)
    const int q    = (flat >> 3) & 3;                  // quarter
    const int u    = ((flat >> 5) << 3) | (flat & 7);  // [0, 832)
    const int set  = u / 416;                          // 26*16 = 416
    const int rem  = u % 416;
    const int n    = rem / 26;
    const int v    = rem % 26;                         // 0..23 feats, 24..25 code
    const bool isF = v < 24;
    const int ks   = isF ? v : v - 24;
    const int g    = ks * 4 + q;                       // 8-channel group index

    const float* src0; float* nrm;
    if (isF) {
        src0 = (set ? f1 : f0) + ((size_t)n * CF + g * 8) * HWP;
        nrm  = nrmF + (size_t)set * NPTP;
    } else {
        src0 = (set ? c1in : c0in) + ((size_t)n * CC + g * 8) * HWP;
        nrm  = nrmC + (size_t)set * NPTP;
    }
    unsigned char* outF = set ? OF1 : OF0;
    short*         outC = set ? OC1 : OC0;
    const float* gr = set ? g1 : g0;
    const int t = threadIdx.x;

    __shared__ float plane[2][4096];   // 2 x 16 KB double buffer (784 f4 used)

    // ---- per-position bilinear meta, computed once ----
    int   po[7], pdx[7], pdw[7];
    float pw[7][4];
    #pragma unroll
    for (int i = 0; i < 7; i++) {
        int p = t + i * 256;
        if (p < PP) {
            float2 gg = *(const float2*)&gr[2 * (n * PP + p)];
            int o00, o01, o10, o11; float w00, w01, w10, w11;
            bilin(gg.x*2.f - 1.f, gg.y*2.f - 1.f, o00, o01, o10, o11, w00, w01, w10, w11);
            po[i] = o00; pdx[i] = o01 - o00; pdw[i] = o10 - o00;
            pw[i][0] = w00; pw[i][1] = w01; pw[i][2] = w10; pw[i][3] = w11;
        } else {
            po[i] = 0; pdx[i] = 0; pdw[i] = 0;
            pw[i][0] = pw[i][1] = pw[i][2] = pw[i][3] = 0.f;   // pad -> exact 0
        }
    }

    auto* pl3 = (__attribute__((address_space(3))) char*)&plane[0][0];

#define ISSUE(C)                                                                    \
    do {                                                                            \
        const char* sp_ = (const char*)(src0 + (C) * HWP);                          \
        _Pragma("unroll")                                                           \
        for (int i_ = 0; i_ < 4; i_++) {                                            \
            int j_  = t + i_ * 256;                                                 \
            int jc_ = min(j_, 783);                                                 \
            __builtin_amdgcn_global_load_lds((gas_p)(sp_ + jc_ * 16),               \
                (las_p)(pl3 + (((C) & 1) * 16384 + j_ * 16)), 16, 0, 0);            \
        }                                                                           \
    } while (0)

    float ss[7];
    float fv[7][8];     // per-position channel values (indices all constant)
    #pragma unroll
    for (int i = 0; i < 7; i++) ss[i] = 0.f;

    ISSUE(0);
    #pragma unroll
    for (int c = 0; c < 8; c++) {
        if (c < 7) {
            ISSUE(c + 1);
            asm volatile("s_waitcnt vmcnt(4)" ::: "memory");   // my ch-c loads done
        } else {
            asm volatile("s_waitcnt vmcnt(0)" ::: "memory");
        }
        __builtin_amdgcn_sched_barrier(0);
        __builtin_amdgcn_s_barrier();              // all waves' ch-c loads done
        const float* pl = &plane[c & 1][0];
        #pragma unroll
        for (int i = 0; i < 7; i++) {
            float val = pw[i][0] * pl[po[i]]
                      + pw[i][1] * pl[po[i] + pdx[i]]
                      + pw[i][2] * pl[po[i] + pdw[i]]
                      + pw[i][3] * pl[po[i] + pdw[i] + pdx[i]];
            ss[i] += val * val;
            fv[i][c] = val;
        }
        __builtin_amdgcn_sched_barrier(0);
        __builtin_amdgcn_s_barrier();              // compute done before reuse
    }
#undef ISSUE

    if (isF) {
        // k-major fp8 layout: [n][24][q=4][p][8 B]; this block owns kchunk q
        const size_t ob = ((size_t)((n * 24 + ks) * 4 + q)) * PPAD * 8;
        #pragma unroll
        for (int i = 0; i < 7; i++) {
            int p = t + i * 256;
            if (p < PPAD) {
                unsigned w0 = 0u, w1 = 0u;
                w0 = __builtin_amdgcn_cvt_pk_fp8_f32(fv[i][0], fv[i][1], w0, 0);
                w0 = __builtin_amdgcn_cvt_pk_fp8_f32(fv[i][2], fv[i][3], w0, 1);
                w1 = __builtin_amdgcn_cvt_pk_fp8_f32(fv[i][4], fv[i][5], w1, 0);
                w1 = __builtin_amdgcn_cvt_pk_fp8_f32(fv[i][6], fv[i][7], w1, 1);
                uint2 w; w.x = w0; w.y = w1;
                *(uint2*)&outF[ob + (size_t)p * 8] = w;
                if (p < PP) atomicAdd(&nrm[n * PPAD + p], ss[i]);
            }
        }
    } else {
        // [n][2][p][32 shorts] bf16 layout (unchanged)
        const size_t ob = ((size_t)(n * 2 + ks)) * PPAD * 32 + q * 8;
        #pragma unroll
        for (int i = 0; i < 7; i++) {
            int p = t + i * 256;
            if (p < PPAD) {
                short ov[8] __attribute__((aligned(16)));
                #pragma unroll
                for (int c = 0; c < 8; c++) {
                    __hip_bfloat16 b = __float2bfloat16(fv[i][c]);
                    ov[c] = *(short*)&b;
                }
                *(short8*)&outC[ob + (size_t)p * 32] = *(const short8*)ov;
                if (p < PP) atomicAdd(&nrm[n * PPAD + p], ss[i]);
            }
        }
    }
}

// ---------------------------------------------------------------------------
// Kernel 2: nrm -> scale (validated round 10). Pad rows -> scale 0.
// ---------------------------------------------------------------------------
__global__ __launch_bounds__(256) void k_nrm(
    const float* __restrict__ nrmF, const float* __restrict__ nrmC,
    float* __restrict__ sclF, float* __restrict__ sclC)
{
    const int i = blockIdx.x * 256 + threadIdx.x;    // [0, 2*NPTP)
    if (i >= 2 * NPTP) return;
    const float* nrm = blockIdx.y ? nrmC : nrmF;
    float*       scl = blockIdx.y ? sclC : sclF;
    const int p = i % PPAD;
    float s = (p < PP) ? 1.f / fmaxf(sqrtf(nrm[i]), 1e-10f) : 0.f;
    scl[i] = s;
}

// ---------------------------------------------------------------------------
// Kernel 3: fused dual correlation GEMM — round 23: round-7 fp8 kernel with
// the fd LDS path TRANSPOSED to k-major to kill the 4-way bank conflict the
// round-7 counters exposed (SQ_LDS_BANK_CONFLICT 2.49e7 -> ~0 expected):
//   global fd [n][24][4][1664][8B]; LDS slab [kchunk=4][128 rows][8B] = 4KB;
//   stage: thread t copies 16B (rows 2(t&63),+1 of kchunk t>>6) -> LDS t*16;
//   read: af = *(long*)&As[fcg*1024 + row*8] — quarter-wave lanes hit 16
//   consecutive 8B granules = all 32 banks once = structural minimum.
// Schedule/ledger/cd path/epilogue byte-identical to validated round-7.
// ---------------------------------------------------------------------------
__global__ __launch_bounds__(256, 3) void k_corr(
    const unsigned char* __restrict__ A, const unsigned char* __restrict__ B,
    const short* __restrict__ C, const short* __restrict__ D,
    const float* __restrict__ sF, const float* __restrict__ sC,
    float* __restrict__ rowfd, float* __restrict__ rowrc, float* __restrict__ t1out)
{
    // XCD-chunked swizzle: 2704 blocks = 8 XCDs x 338; x fastest within chunk
    const int flat = blockIdx.x;
    const int v   = (flat & 7) * 338 + (flat >> 3);
    const int n   = v / 169;
    const int rr  = v - n * 169;
    const int bp1 = (rr / 13) * 128;
    const int bp2 = (rr % 13) * 128;

    __shared__ char Asb[3][8192];   // 3 buffers x 8 KB (cd bf16 slab / fd fp8 slab)
    __shared__ char Bsb[3][8192];

    const int t    = threadIdx.x;
    const int wv   = t >> 6, lane = t & 63;
    const int wm   = wv >> 1, wn = wv & 1;
    const int frow = lane & 15, fcg = lane >> 4;     // fragment row / k-chunk
    const int fslot = fcg ^ ((frow >> 1) & 3);       // bank-swizzled slot (cd bf16)

    // ---- cd (bf16) staging geometry: chunk g = (wv*2+i)*64 + lane, [0,512)
    const int sg0  = wv * 2 * 64 + lane;
    const int row0 = sg0 >> 2,        cg0 = (sg0 & 3) ^ ((row0 >> 1) & 3);
    const int sg1  = sg0 + 64;
    const int row1 = sg1 >> 2,        cg1 = (sg1 & 3) ^ ((row1 >> 1) & 3);
    const size_t kstep_s = (size_t)PPAD * 32;        // shorts per bf16 BK=32 slab
    const short* cdC = C + (size_t)n * 2 * kstep_s;
    const short* cdD = D + (size_t)n * 2 * kstep_s;
    const size_t toA0 = (size_t)(bp1 + row0) * 32 + cg0 * 8;
    const size_t toA1 = (size_t)(bp1 + row1) * 32 + cg1 * 8;
    const size_t toB0 = (size_t)(bp2 + row0) * 32 + cg0 * 8;
    const size_t toB1 = (size_t)(bp2 + row1) * 32 + cg1 * 8;
    auto* As3s = (__attribute__((address_space(3))) short*)&Asb[0][0];
    auto* Bs3s = (__attribute__((address_space(3))) short*)&Bsb[0][0];
    const short* AsS = (const short*)&Asb[0][0];
    const short* BsS = (const short*)&Bsb[0][0];
    const int ldsA0 = (wv * 2    ) * 512;  // shorts within one 4096-short buffer
    const int ldsA1 = (wv * 2 + 1) * 512;

    // ---- fd (fp8) staging geometry, k-major ----
    // global slab (one BK=32 step): [kchunk=4][1664][8B] = PPAD*32 bytes
    const size_t FDSTEP = (size_t)PPAD * 32;         // BYTES per fp8 BK=32 slab
    const unsigned char* fdA = A + (size_t)n * 24 * FDSTEP;
    const unsigned char* fdB = B + (size_t)n * 24 * FDSTEP;
    // thread t stages 16B: kchunk t>>6, tile rows 2*(t&63), 2*(t&63)+1
    const size_t toAf = (size_t)(t >> 6) * (PPAD * 8) + (size_t)(bp1 + 2 * (t & 63)) * 8;
    const size_t toBf = (size_t)(t >> 6) * (PPAD * 8) + (size_t)(bp2 + 2 * (t & 63)) * 8;
    auto* Asb3 = (__attribute__((address_space(3))) char*)&Asb[0][0];
    auto* Bsb3 = (__attribute__((address_space(3))) char*)&Bsb[0][0];
    const int fldsW = wv * 1024;   // wave-uniform byte base (+lane*16 implicit)

#define STAGECD(BUF, OFF)                                                           \
    do {                                                                            \
        const size_t off_ = (OFF);                                                  \
        const int b_ = (BUF) * 4096;                                                \
        __builtin_amdgcn_global_load_lds((gas_p)(cdC + toA0 + off_),                \
                                         (las_p)(As3s + b_ + ldsA0), 16, 0, 0);     \
        __builtin_amdgcn_global_load_lds((gas_p)(cdC + toA1 + off_),                \
                                         (las_p)(As3s + b_ + ldsA1), 16, 0, 0);     \
        __builtin_amdgcn_global_load_lds((gas_p)(cdD + toB0 + off_),                \
                                         (las_p)(Bs3s + b_ + ldsA0), 16, 0, 0);     \
        __builtin_amdgcn_global_load_lds((gas_p)(cdD + toB1 + off_),                \
                                         (las_p)(Bs3s + b_ + ldsA1), 16, 0, 0);     \
    } while (0)

#define STAGEF(OFF, BUF)                                                            \
    do {                                                                            \
        const size_t off_ = (OFF);                                                  \
        __builtin_amdgcn_global_load_lds((gas_p)(fdA + toAf + off_),                \
                                         (las_p)(Asb3 + (BUF) * 8192 + fldsW), 16, 0, 0); \
        __builtin_amdgcn_global_load_lds((gas_p)(fdB + toBf + off_),                \
                                         (las_p)(Bsb3 + (BUF) * 8192 + fldsW), 16, 0, 0); \
    } while (0)

#define COMPUTECD(BUF, ACC)                                                         \
    do {                                                                            \
        short8 af[4], bf[4];                                                        \
        _Pragma("unroll")                                                           \
        for (int m = 0; m < 4; m++)                                                 \
            af[m] = *(const short8*)&AsS[(BUF)*4096 + (wm*64 + m*16 + frow)*32 + fslot*8]; \
        _Pragma("unroll")                                                           \
        for (int q = 0; q < 4; q++)                                                 \
            bf[q] = *(const short8*)&BsS[(BUF)*4096 + (wn*64 + q*16 + frow)*32 + fslot*8]; \
        _Pragma("unroll")                                                           \
        for (int m = 0; m < 4; m++)                                                 \
            _Pragma("unroll")                                                       \
            for (int q = 0; q < 4; q++)                                             \
                ACC[m][q] = __builtin_amdgcn_mfma_f32_16x16x32_bf16(af[m], bf[q], ACC[m][q], 0, 0, 0); \
    } while (0)

// k-major fd reads: quarter-wave (fixed fcg) reads 16 consecutive 8B granules
#define COMPUTEF(BUF, ACC)                                                          \
    do {                                                                            \
        long af[4], bf[4];                                                          \
        _Pragma("unroll")                                                           \
        for (int m = 0; m < 4; m++)                                                 \
            af[m] = *(const long*)&Asb[BUF][fcg*1024 + (wm*64 + m*16 + frow)*8];    \
        _Pragma("unroll")                                                           \
        for (int q = 0; q < 4; q++)                                                 \
            bf[q] = *(const long*)&Bsb[BUF][fcg*1024 + (wn*64 + q*16 + frow)*8];    \
        _Pragma("unroll")                                                           \
        for (int m = 0; m < 4; m++)                                                 \
            _Pragma("unroll")                                                       \
            for (int q = 0; q < 4; q++)                                             \
                ACC[m][q] = __builtin_amdgcn_mfma_f32_16x16x32_fp8_fp8(af[m], bf[q], ACC[m][q], 0, 0, 0); \
    } while (0)

#define WAITV4  do { asm volatile("s_waitcnt vmcnt(4)" ::: "memory");               \
                     __builtin_amdgcn_sched_barrier(0);                             \
                     __builtin_amdgcn_s_barrier(); } while (0)
#define WAITV2  do { asm volatile("s_waitcnt vmcnt(2)" ::: "memory");               \
                     __builtin_amdgcn_sched_barrier(0);                             \
                     __builtin_amdgcn_s_barrier(); } while (0)
#define WAITV0  do { asm volatile("s_waitcnt vmcnt(0)" ::: "memory");               \
                     __builtin_amdgcn_sched_barrier(0);                             \
                     __builtin_amdgcn_s_barrier(); } while (0)

    unsigned pcd[4][4][2];   // raw relu(cd) packed as bf16 pairs (32 VGPR)

    // ---- prologue: stage cd steps 0,1 (4 glds each) ----
    STAGECD(0, 0);
    STAGECD(1, kstep_s);

    // ---- cd slots 0,1 ----
    {
        f32x4 acccd[4][4];
        #pragma unroll
        for (int m = 0; m < 4; m++)
            #pragma unroll
            for (int q = 0; q < 4; q++)
                #pragma unroll
                for (int r = 0; r < 4; r++) acccd[m][q][r] = 0.f;

        WAITV4;                         // cd0 landed (cd1's 4 in flight)
        STAGEF(0, 2);                   // fd step 0 -> buf2 (+2)
        COMPUTECD(0, acccd);
        WAITV2;                         // cd1 landed (fd0's 2 in flight)
        STAGEF(1 * FDSTEP, 0);          // fd step 1 -> buf0 (+2)
        COMPUTECD(1, acccd);

        // pack raw relu(cd) -> bf16 pairs (pure VALU; scales deferred)
        #pragma unroll
        for (int m = 0; m < 4; m++)
            #pragma unroll
            for (int q = 0; q < 4; q++) {
                float r0 = fmaxf(acccd[m][q][0], 0.f);
                float r1 = fmaxf(acccd[m][q][1], 0.f);
                float r2 = fmaxf(acccd[m][q][2], 0.f);
                float r3 = fmaxf(acccd[m][q][3], 0.f);
                pcd[m][q][0] = f2b(r0) | (f2b(r1) << 16);
                pcd[m][q][1] = f2b(r2) | (f2b(r3) << 16);
            }
    }   // acccd dies (AGPRs freed before accfd)

    // ---- fd slots: 24 steps, step j in buf (2+j)%3, stage 2-ahead ----
    f32x4 accfd[4][4];
    #pragma unroll
    for (int m = 0; m < 4; m++)
        #pragma unroll
        for (int q = 0; q < 4; q++)
            #pragma unroll
            for (int r = 0; r < 4; r++) accfd[m][q][r] = 0.f;

    for (int kp = 0; kp < 8; kp++) {
        const size_t tb = (size_t)(3 * kp) * FDSTEP;
        // slot: compute fd 3kp (buf2), stage fd 3kp+2 -> buf1
        WAITV2;
        STAGEF(tb + 2 * FDSTEP, 1);
        COMPUTEF(2, accfd);
        // slot: compute fd 3kp+1 (buf0), stage fd 3kp+3 -> buf2
        WAITV2;
        if (kp < 7) STAGEF(tb + 3 * FDSTEP, 2);
        COMPUTEF(0, accfd);
        // slot: compute fd 3kp+2 (buf1), stage fd 3kp+4 -> buf0
        if (kp < 7) {
            WAITV2;
            STAGEF(tb + 4 * FDSTEP, 0);
        } else {
            WAITV0;
        }
        COMPUTEF(1, accfd);
    }
#undef STAGECD
#undef STAGEF
#undef COMPUTECD
#undef COMPUTEF
#undef WAITV4
#undef WAITV2
#undef WAITV0

    // ---- single deferred epilogue: scales + t1 + rowfd + rowrc ----
    // C/D layout: col = lane&15, row = (lane>>4)*4 + reg (dtype-independent)
    float scc_[4], sfc_[4];
    #pragma unroll
    for (int q = 0; q < 4; q++) {
        size_t colp = (size_t)NPTP + (size_t)n * PPAD + bp2 + wn*64 + q*16 + frow;
        scc_[q] = sC[colp];
        sfc_[q] = sF[colp];
    }

    float t1 = 0.f;
    #pragma unroll
    for (int m = 0; m < 4; m++) {
        #pragma unroll
        for (int r = 0; r < 4; r++) {
            size_t rowp = (size_t)n * PPAD + bp1 + wm*64 + m*16 + fcg*4 + r;
            float scr = sC[rowp];
            float sfr = sF[rowp];
            float sf = 0.f, sr = 0.f;
            #pragma unroll
            for (int q = 0; q < 4; q++) {
                float fdv = accfd[m][q][r] * sfr * sfc_[q];
                float rcv = bup(pcd[m][q][r >> 1], r & 1) * scr * scc_[q];
                t1 += rcv * fdv;
                sf += fdv;
                sr += rcv;
            }
            #pragma unroll
            for (int d = 1; d < 16; d <<= 1) {
                sf += __shfl_xor(sf, d, 64);
                sr += __shfl_xor(sr, d, 64);
            }
            if ((lane & 15) == 0) {
                int row = bp1 + wm*64 + m*16 + fcg*4 + r;
                atomicAdd(&rowfd[n * PPAD + row], sf);
                atomicAdd(&rowrc[n * PPAD + row], sr);
            }
        }
    }
    #pragma unroll
    for (int d = 1; d < 64; d <<= 1) t1 += __shfl_xor(t1, d, 64);
    __shared__ float t1s[4];
    if (lane == 0) t1s[wv] = t1;
    __syncthreads();
    if (t == 0) atomicAdd(t1out, t1s[0] + t1s[1] + t1s[2] + t1s[3]);
}

// ---------------------------------------------------------------------------
// Kernel 4: finalize. loss = -(T1 - cross/PP + (Sfd/M)*Src)/M
// ---------------------------------------------------------------------------
__global__ __launch_bounds__(1024) void k_final(
    const float* __restrict__ rowfd, const float* __restrict__ rowrc,
    const float* __restrict__ t1p, float* __restrict__ out)
{
    const int t = threadIdx.x;
    double cr = 0.0, sf = 0.0, sr = 0.0;
    for (int i = t; i < NN * PPAD; i += 1024) {
        double a = rowfd[i], b = rowrc[i];
        cr += a * b; sf += a; sr += b;
    }
    __shared__ double sh[1024];
    sh[t] = cr; __syncthreads();
    for (int s = 512; s > 0; s >>= 1) { if (t < s) sh[t] += sh[t + s]; __syncthreads(); }
    cr = sh[0]; __syncthreads();
    sh[t] = sf; __syncthreads();
    for (int s = 512; s > 0; s >>= 1) { if (t < s) sh[t] += sh[t + s]; __syncthreads(); }
    sf = sh[0]; __syncthreads();
    sh[t] = sr; __syncthreads();
    for (int s = 512; s > 0; s >>= 1) { if (t < s) sh[t] += sh[t + s]; __syncthreads(); }
    sr = sh[0];
    if (t == 0) {
        double M = (double)NN * (double)PP * (double)PP;
        double t1 = (double)t1p[0];
        double bracket = t1 - cr / (double)PP + (sf / M) * sr;
        out[0] = (float)(-bracket / M);
    }
}

// ---------------------------------------------------------------------------
extern "C" void kernel_launch(void* const* d_in, const int* in_sizes, int n_in,
                              void* d_out, int out_size, void* d_ws, size_t ws_size,
                              hipStream_t stream)
{
    const float* orig_feats     = (const float*)d_in[0];
    const float* orig_feats_pos = (const float*)d_in[1];
    const float* orig_code      = (const float*)d_in[2];
    const float* orig_code_pos  = (const float*)d_in[3];
    const float* coords1        = (const float*)d_in[4];
    const float* coords2        = (const float*)d_in[5];

    // ---- workspace layout ----
    char* ws = (char*)d_ws;
    float* t1    = (float*)(ws + 0);                      //      256 B
    float* rowfd = (float*)(ws + 256);                    //  106,496 B (NN*PPAD)
    float* rowrc = (float*)(ws + 106752);                 //  106,496 B
    float* nrmF  = (float*)(ws + 213248);                 //  212,992 B (2*NPTP)
    float* nrmC  = (float*)(ws + 426240);                 //  212,992 B
    const size_t zeroBytes = 639232;                      // t1+rowsums+nrms
    float* sclF  = (float*)(ws + 639232);                 //  212,992 B
    float* sclC  = (float*)(ws + 852224);                 //  212,992 B
    unsigned char* OF0 = (unsigned char*)(ws + 1065216);  // [16][24][4][1664][8B] fp8
    unsigned char* OF1 = (unsigned char*)(ws + 1065216 + 20447232ull);
    short* OC0 = (short*)(ws + 1065216 + 2*20447232ull);  // [16][2][1664][32] bf16
    short* OC1 = (short*)(ws + 1065216 + 2*20447232ull + 3407872ull);

    (void)hipMemsetAsync(d_ws, 0, zeroBytes, stream);   // t1/rowsums/nrms

    k_sample<<<dim3(3328), 256, 0, stream>>>(
        orig_feats, orig_feats_pos, orig_code, orig_code_pos,
        coords1, coords2, nrmF, nrmC, OF0, OF1, OC0, OC1);

    k_nrm<<<dim3((2*NPTP + 255)/256, 2), 256, 0, stream>>>(
        nrmF, nrmC, sclF, sclC);

    k_corr<<<dim3(2704), 256, 0, stream>>>(
        OF0, OF1, OC0, OC1, sclF, sclC, rowfd, rowrc, t1);

    k_final<<<1, 1024, 0, stream>>>(rowfd, rowrc, t1, (float*)d_out);
}

// Round 9
// 211.459 us; speedup vs baseline: 1.2472x; 1.0293x over previous
//
#include <hip/hip_runtime.h>
#include <hip/hip_bf16.h>

// Problem constants
#define NN 16
#define CF 768
#define CC 64
#define HH 56
#define WW 56
#define SS 40
#define PP (SS*SS)          // 1600 positions per image
#define PPAD 1664           // padded to 13*128 for 128-tile GEMM
#define NPT (NN*PP)         // 25600
#define NPTP (NN*PPAD)      // 26624
#define HWP (HH*WW)         // 3136

typedef __attribute__((ext_vector_type(8))) short short8;
typedef __attribute__((ext_vector_type(4))) float f32x4;

typedef const __attribute__((address_space(1))) void* gas_p;
typedef __attribute__((address_space(3))) void* las_p;

__device__ __forceinline__ unsigned f2b(float f) {
    __hip_bfloat16 b = __float2bfloat16(f);
    return (unsigned)*(unsigned short*)&b;
}
__device__ __forceinline__ float bup(unsigned u, int hi) {
    unsigned bits = hi ? (u & 0xffff0000u) : (u << 16);
    return __uint_as_float(bits);
}

// Shared bilinear helper — EXACT same arithmetic as validated round-1 kernel.
__device__ __forceinline__ void bilin(float gx, float gy,
    int& o00, int& o01, int& o10, int& o11,
    float& w00, float& w01, float& w10, float& w11)
{
    float x = (gx + 1.f) * 0.5f * (float)(WW - 1);
    float y = (gy + 1.f) * 0.5f * (float)(HH - 1);
    x = fminf(fmaxf(x, 0.f), (float)(WW - 1));
    y = fminf(fmaxf(y, 0.f), (float)(HH - 1));
    float xf = floorf(x), yf = floorf(y);
    int x0 = (int)xf, y0 = (int)yf;
    int x1 = min(x0 + 1, WW - 1), y1 = min(y0 + 1, HH - 1);
    float wx = x - xf, wy = y - yf;
    w00 = (1.f-wx)*(1.f-wy); w01 = wx*(1.f-wy); w10 = (1.f-wx)*wy; w11 = wx*wy;
    o00 = y0*WW + x0; o01 = y0*WW + x1; o10 = y1*WW + x0; o11 = y1*WW + x1;
}

// ---------------------------------------------------------------------------
// Kernel 1: sampling — VERBATIM round-8 (validated): fp8 k-major feats
// [n][24][4][1664][8B], bf16 code [n][2][1664][32 shorts].
// ---------------------------------------------------------------------------
__global__ __launch_bounds__(256) void k_sample(
    const float* __restrict__ f0, const float* __restrict__ f1,
    const float* __restrict__ c0in, const float* __restrict__ c1in,
    const float* __restrict__ g0, const float* __restrict__ g1,
    float* __restrict__ nrmF, float* __restrict__ nrmC,
    unsigned char* __restrict__ OF0, unsigned char* __restrict__ OF1,
    short* __restrict__ OC0, short* __restrict__ OC1)
{
    // decode quarter-interleaved flat index (identical to validated kernel)
    const int flat = blockIdx.x;                       // [0, 3328)
    const int q    = (flat >> 3) & 3;                  // quarter
    const int u    = ((flat >> 5) << 3) | (flat & 7);  // [0, 832)
    const int set  = u / 416;                          // 26*16 = 416
    const int rem  = u % 416;
    const int n    = rem / 26;
    const int v    = rem % 26;                         // 0..23 feats, 24..25 code
    const bool isF = v < 24;
    const int ks   = isF ? v : v - 24;
    const int g    = ks * 4 + q;                       // 8-channel group index

    const float* src0; float* nrm;
    if (isF) {
        src0 = (set ? f1 : f0) + ((size_t)n * CF + g * 8) * HWP;
        nrm  = nrmF + (size_t)set * NPTP;
    } else {
        src0 = (set ? c1in : c0in) + ((size_t)n * CC + g * 8) * HWP;
        nrm  = nrmC + (size_t)set * NPTP;
    }
    unsigned char* outF = set ? OF1 : OF0;
    short*         outC = set ? OC1 : OC0;
    const float* gr = set ? g1 : g0;
    const int t = threadIdx.x;

    __shared__ float plane[2][4096];   // 2 x 16 KB double buffer (784 f4 used)

    // ---- per-position bilinear meta, computed once ----
    int   po[7], pdx[7], pdw[7];
    float pw[7][4];
    #pragma unroll
    for (int i = 0; i < 7; i++) {
        int p = t + i * 256;
        if (p < PP) {
            float2 gg = *(const float2*)&gr[2 * (n * PP + p)];
            int o00, o01, o10, o11; float w00, w01, w10, w11;
            bilin(gg.x*2.f - 1.f, gg.y*2.f - 1.f, o00, o01, o10, o11, w00, w01, w10, w11);
            po[i] = o00; pdx[i] = o01 - o00; pdw[i] = o10 - o00;
            pw[i][0] = w00; pw[i][1] = w01; pw[i][2] = w10; pw[i][3] = w11;
        } else {
            po[i] = 0; pdx[i] = 0; pdw[i] = 0;
            pw[i][0] = pw[i][1] = pw[i][2] = pw[i][3] = 0.f;   // pad -> exact 0
        }
    }

    auto* pl3 = (__attribute__((address_space(3))) char*)&plane[0][0];

#define ISSUE(C)                                                                    \
    do {                                                                            \
        const char* sp_ = (const char*)(src0 + (C) * HWP);                          \
        _Pragma("unroll")                                                           \
        for (int i_ = 0; i_ < 4; i_++) {                                            \
            int j_  = t + i_ * 256;                                                 \
            int jc_ = min(j_, 783);                                                 \
            __builtin_amdgcn_global_load_lds((gas_p)(sp_ + jc_ * 16),               \
                (las_p)(pl3 + (((C) & 1) * 16384 + j_ * 16)), 16, 0, 0);            \
        }                                                                           \
    } while (0)

    float ss[7];
    float fv[7][8];     // per-position channel values (indices all constant)
    #pragma unroll
    for (int i = 0; i < 7; i++) ss[i] = 0.f;

    ISSUE(0);
    #pragma unroll
    for (int c = 0; c < 8; c++) {
        if (c < 7) {
            ISSUE(c + 1);
            asm volatile("s_waitcnt vmcnt(4)" ::: "memory");   // my ch-c loads done
        } else {
            asm volatile("s_waitcnt vmcnt(0)" ::: "memory");
        }
        __builtin_amdgcn_sched_barrier(0);
        __builtin_amdgcn_s_barrier();              // all waves' ch-c loads done
        const float* pl = &plane[c & 1][0];
        #pragma unroll
        for (int i = 0; i < 7; i++) {
            float val = pw[i][0] * pl[po[i]]
                      + pw[i][1] * pl[po[i] + pdx[i]]
                      + pw[i][2] * pl[po[i] + pdw[i]]
                      + pw[i][3] * pl[po[i] + pdw[i] + pdx[i]];
            ss[i] += val * val;
            fv[i][c] = val;
        }
        __builtin_amdgcn_sched_barrier(0);
        __builtin_amdgcn_s_barrier();              // compute done before reuse
    }
#undef ISSUE

    if (isF) {
        // k-major fp8 layout: [n][24][q=4][p][8 B]; this block owns kchunk q
        const size_t ob = ((size_t)((n * 24 + ks) * 4 + q)) * PPAD * 8;
        #pragma unroll
        for (int i = 0; i < 7; i++) {
            int p = t + i * 256;
            if (p < PPAD) {
                unsigned w0 = 0u, w1 = 0u;
                w0 = __builtin_amdgcn_cvt_pk_fp8_f32(fv[i][0], fv[i][1], w0, 0);
                w0 = __builtin_amdgcn_cvt_pk_fp8_f32(fv[i][2], fv[i][3], w0, 1);
                w1 = __builtin_amdgcn_cvt_pk_fp8_f32(fv[i][4], fv[i][5], w1, 0);
                w1 = __builtin_amdgcn_cvt_pk_fp8_f32(fv[i][6], fv[i][7], w1, 1);
                uint2 w; w.x = w0; w.y = w1;
                *(uint2*)&outF[ob + (size_t)p * 8] = w;
                if (p < PP) atomicAdd(&nrm[n * PPAD + p], ss[i]);
            }
        }
    } else {
        // [n][2][p][32 shorts] bf16 layout (unchanged)
        const size_t ob = ((size_t)(n * 2 + ks)) * PPAD * 32 + q * 8;
        #pragma unroll
        for (int i = 0; i < 7; i++) {
            int p = t + i * 256;
            if (p < PPAD) {
                short ov[8] __attribute__((aligned(16)));
                #pragma unroll
                for (int c = 0; c < 8; c++) {
                    __hip_bfloat16 b = __float2bfloat16(fv[i][c]);
                    ov[c] = *(short*)&b;
                }
                *(short8*)&outC[ob + (size_t)p * 32] = *(const short8*)ov;
                if (p < PP) atomicAdd(&nrm[n * PPAD + p], ss[i]);
            }
        }
    }
}

// ---------------------------------------------------------------------------
// Kernel 2: nrm -> scale (validated round 10). Pad rows -> scale 0.
// ---------------------------------------------------------------------------
__global__ __launch_bounds__(256) void k_nrm(
    const float* __restrict__ nrmF, const float* __restrict__ nrmC,
    float* __restrict__ sclF, float* __restrict__ sclC)
{
    const int i = blockIdx.x * 256 + threadIdx.x;    // [0, 2*NPTP)
    if (i >= 2 * NPTP) return;
    const float* nrm = blockIdx.y ? nrmC : nrmF;
    float*       scl = blockIdx.y ? sclC : sclF;
    const int p = i % PPAD;
    float s = (p < PP) ? 1.f / fmaxf(sqrtf(nrm[i]), 1e-10f) : 0.f;
    scl[i] = s;
}

// ---------------------------------------------------------------------------
// Kernel 3: fused dual correlation GEMM — round 24: round-8 fp8 k-major
// kernel with fd slots widened to BK=64 (12 fd slots + 2 cd slots instead of
// 24+2). Rationale: fp8 halved the staging floor to ~88us, exposing ~43us of
// per-slot sync overhead at 26 slots (r5 showed BK=64 neutral at bf16 only
// because the 6.8TB/s staging floor masked it). Buffers: 3 x 8KB per operand
// (unchanged LDS total). fd tile = [8 kchunk][128 row][8B]; stage = 4 glds
// (each wave fills kchunks wv*2, wv*2+1); read kc = kk*4+fcg — round-8's
// conflict-free pattern verbatim. Uniform ledger: 4 glds/stage, WAITV4
// everywhere, final V0. cd path / epilogue / k_sample byte-identical to the
// passing round-8 kernel.
// ---------------------------------------------------------------------------
__global__ __launch_bounds__(256, 3) void k_corr(
    const unsigned char* __restrict__ A, const unsigned char* __restrict__ B,
    const short* __restrict__ C, const short* __restrict__ D,
    const float* __restrict__ sF, const float* __restrict__ sC,
    float* __restrict__ rowfd, float* __restrict__ rowrc, float* __restrict__ t1out)
{
    // XCD-chunked swizzle: 2704 blocks = 8 XCDs x 338; x fastest within chunk
    const int flat = blockIdx.x;
    const int v   = (flat & 7) * 338 + (flat >> 3);
    const int n   = v / 169;
    const int rr  = v - n * 169;
    const int bp1 = (rr / 13) * 128;
    const int bp2 = (rr % 13) * 128;

    __shared__ char Asb[3][8192];   // 3 buffers x 8 KB (cd bf16 slab / fd fp8 BK=64 tile)
    __shared__ char Bsb[3][8192];

    const int t    = threadIdx.x;
    const int wv   = t >> 6, lane = t & 63;
    const int wm   = wv >> 1, wn = wv & 1;
    const int frow = lane & 15, fcg = lane >> 4;     // fragment row / k-chunk
    const int fslot = fcg ^ ((frow >> 1) & 3);       // bank-swizzled slot (cd bf16)

    // ---- cd (bf16) staging geometry: chunk g = (wv*2+i)*64 + lane, [0,512)
    const int sg0  = wv * 2 * 64 + lane;
    const int row0 = sg0 >> 2,        cg0 = (sg0 & 3) ^ ((row0 >> 1) & 3);
    const int sg1  = sg0 + 64;
    const int row1 = sg1 >> 2,        cg1 = (sg1 & 3) ^ ((row1 >> 1) & 3);
    const size_t kstep_s = (size_t)PPAD * 32;        // shorts per bf16 BK=32 slab
    const short* cdC = C + (size_t)n * 2 * kstep_s;
    const short* cdD = D + (size_t)n * 2 * kstep_s;
    const size_t toA0 = (size_t)(bp1 + row0) * 32 + cg0 * 8;
    const size_t toA1 = (size_t)(bp1 + row1) * 32 + cg1 * 8;
    const size_t toB0 = (size_t)(bp2 + row0) * 32 + cg0 * 8;
    const size_t toB1 = (size_t)(bp2 + row1) * 32 + cg1 * 8;
    auto* As3s = (__attribute__((address_space(3))) short*)&Asb[0][0];
    auto* Bs3s = (__attribute__((address_space(3))) short*)&Bsb[0][0];
    const short* AsS = (const short*)&Asb[0][0];
    const short* BsS = (const short*)&Bsb[0][0];
    const int ldsA0 = (wv * 2    ) * 512;  // shorts within one 4096-short buffer
    const int ldsA1 = (wv * 2 + 1) * 512;

    // ---- fd (fp8) staging geometry, k-major, BK=64 ----
    // global: [n][24 steps][4][PPAD][8B] = linear kchunks 0..95, kchunk K at
    // byte K*(PPAD*8). BK=64 tile T = kchunks 8T..8T+7, FDTILE bytes apart.
    const size_t FDTILE = (size_t)PPAD * 64;         // BYTES per fp8 BK=64 tile
    const unsigned char* fdA = A + (size_t)n * 24 * ((size_t)PPAD * 32);
    const unsigned char* fdB = B + (size_t)n * 24 * ((size_t)PPAD * 32);
    // wave wv, glds j in {0,1}: fills LDS kchunk (wv*2+j); lane covers rows
    // 2*lane, 2*lane+1 (16B). Global src = kchunk byte base + (bp+2*lane)*8.
    const size_t toAf0 = (size_t)(wv * 2    ) * (PPAD * 8) + (size_t)(bp1 + 2 * lane) * 8;
    const size_t toAf1 = (size_t)(wv * 2 + 1) * (PPAD * 8) + (size_t)(bp1 + 2 * lane) * 8;
    const size_t toBf0 = (size_t)(wv * 2    ) * (PPAD * 8) + (size_t)(bp2 + 2 * lane) * 8;
    const size_t toBf1 = (size_t)(wv * 2 + 1) * (PPAD * 8) + (size_t)(bp2 + 2 * lane) * 8;
    auto* Asb3 = (__attribute__((address_space(3))) char*)&Asb[0][0];
    auto* Bsb3 = (__attribute__((address_space(3))) char*)&Bsb[0][0];
    const int fldsW0 = (wv * 2    ) * 1024;   // wave-uniform byte base (+lane*16)
    const int fldsW1 = (wv * 2 + 1) * 1024;

#define STAGECD(BUF, OFF)                                                           \
    do {                                                                            \
        const size_t off_ = (OFF);                                                  \
        const int b_ = (BUF) * 4096;                                                \
        __builtin_amdgcn_global_load_lds((gas_p)(cdC + toA0 + off_),                \
                                         (las_p)(As3s + b_ + ldsA0), 16, 0, 0);     \
        __builtin_amdgcn_global_load_lds((gas_p)(cdC + toA1 + off_),                \
                                         (las_p)(As3s + b_ + ldsA1), 16, 0, 0);     \
        __builtin_amdgcn_global_load_lds((gas_p)(cdD + toB0 + off_),                \
                                         (las_p)(Bs3s + b_ + ldsA0), 16, 0, 0);     \
        __builtin_amdgcn_global_load_lds((gas_p)(cdD + toB1 + off_),                \
                                         (las_p)(Bs3s + b_ + ldsA1), 16, 0, 0);     \
    } while (0)

// stage one BK=64 fp8 tile (8 KB/operand) into buffer BUF: 4 glds/thread
#define STAGEF(TILE, BUF)                                                           \
    do {                                                                            \
        const size_t off_ = (size_t)(TILE) * FDTILE;                                \
        __builtin_amdgcn_global_load_lds((gas_p)(fdA + toAf0 + off_),               \
                                         (las_p)(Asb3 + (BUF) * 8192 + fldsW0), 16, 0, 0); \
        __builtin_amdgcn_global_load_lds((gas_p)(fdA + toAf1 + off_),               \
                                         (las_p)(Asb3 + (BUF) * 8192 + fldsW1), 16, 0, 0); \
        __builtin_amdgcn_global_load_lds((gas_p)(fdB + toBf0 + off_),               \
                                         (las_p)(Bsb3 + (BUF) * 8192 + fldsW0), 16, 0, 0); \
        __builtin_amdgcn_global_load_lds((gas_p)(fdB + toBf1 + off_),               \
                                         (las_p)(Bsb3 + (BUF) * 8192 + fldsW1), 16, 0, 0); \
    } while (0)

#define COMPUTECD(BUF, ACC)                                                         \
    do {                                                                            \
        short8 af[4], bf[4];                                                        \
        _Pragma("unroll")                                                           \
        for (int m = 0; m < 4; m++)                                                 \
            af[m] = *(const short8*)&AsS[(BUF)*4096 + (wm*64 + m*16 + frow)*32 + fslot*8]; \
        _Pragma("unroll")                                                           \
        for (int q = 0; q < 4; q++)                                                 \
            bf[q] = *(const short8*)&BsS[(BUF)*4096 + (wn*64 + q*16 + frow)*32 + fslot*8]; \
        _Pragma("unroll")                                                           \
        for (int m = 0; m < 4; m++)                                                 \
            _Pragma("unroll")                                                       \
            for (int q = 0; q < 4; q++)                                             \
                ACC[m][q] = __builtin_amdgcn_mfma_f32_16x16x32_bf16(af[m], bf[q], ACC[m][q], 0, 0, 0); \
    } while (0)

// BK=64 fp8 compute: 2 K-substeps; LDS kchunk = kk*4 + fcg; quarter-wave
// reads 16 consecutive 8B granules (all 32 banks once) — conflict-free.
#define COMPUTEF64(BUF, ACC)                                                        \
    do {                                                                            \
        _Pragma("unroll")                                                           \
        for (int kk_ = 0; kk_ < 2; kk_++) {                                         \
            long af[4], bf[4];                                                      \
            const int kb_ = (BUF) * 8192 + (kk_ * 4 + fcg) * 1024;                  \
            _Pragma("unroll")                                                       \
            for (int m = 0; m < 4; m++)                                             \
                af[m] = *(const long*)&Asb[0][kb_ + (wm*64 + m*16 + frow)*8];       \
            _Pragma("unroll")                                                       \
            for (int q = 0; q < 4; q++)                                             \
                bf[q] = *(const long*)&Bsb[0][kb_ + (wn*64 + q*16 + frow)*8];       \
            _Pragma("unroll")                                                       \
            for (int m = 0; m < 4; m++)                                             \
                _Pragma("unroll")                                                   \
                for (int q = 0; q < 4; q++)                                         \
                    ACC[m][q] = __builtin_amdgcn_mfma_f32_16x16x32_fp8_fp8(af[m], bf[q], ACC[m][q], 0, 0, 0); \
        }                                                                           \
    } while (0)

#define WAITV4  do { asm volatile("s_waitcnt vmcnt(4)" ::: "memory");               \
                     __builtin_amdgcn_sched_barrier(0);                             \
                     __builtin_amdgcn_s_barrier(); } while (0)
#define WAITV0  do { asm volatile("s_waitcnt vmcnt(0)" ::: "memory");               \
                     __builtin_amdgcn_sched_barrier(0);                             \
                     __builtin_amdgcn_s_barrier(); } while (0)

    unsigned pcd[4][4][2];   // raw relu(cd) packed as bf16 pairs (32 VGPR)

    // ---- prologue: stage cd steps 0,1 (4 glds each) ----
    STAGECD(0, 0);
    STAGECD(1, kstep_s);

    // ---- cd slots 0,1 ----
    {
        f32x4 acccd[4][4];
        #pragma unroll
        for (int m = 0; m < 4; m++)
            #pragma unroll
            for (int q = 0; q < 4; q++)
                #pragma unroll
                for (int r = 0; r < 4; r++) acccd[m][q][r] = 0.f;

        WAITV4;                         // cd0 landed (cd1's 4 in flight)
        STAGEF(0, 2);                   // fd tile 0 -> buf2 (+4)
        COMPUTECD(0, acccd);
        WAITV4;                         // cd1 landed (fd0's 4 in flight)
        STAGEF(1, 0);                   // fd tile 1 -> buf0 (+4)
        COMPUTECD(1, acccd);

        // pack raw relu(cd) -> bf16 pairs (pure VALU; scales deferred)
        #pragma unroll
        for (int m = 0; m < 4; m++)
            #pragma unroll
            for (int q = 0; q < 4; q++) {
                float r0 = fmaxf(acccd[m][q][0], 0.f);
                float r1 = fmaxf(acccd[m][q][1], 0.f);
                float r2 = fmaxf(acccd[m][q][2], 0.f);
                float r3 = fmaxf(acccd[m][q][3], 0.f);
                pcd[m][q][0] = f2b(r0) | (f2b(r1) << 16);
                pcd[m][q][1] = f2b(r2) | (f2b(r3) << 16);
            }
    }   // acccd dies (AGPRs freed before accfd)

    // ---- fd slots: 12 BK=64 tiles, tile j in buf (2+j)%3, stage 2-ahead ----
    f32x4 accfd[4][4];
    #pragma unroll
    for (int m = 0; m < 4; m++)
        #pragma unroll
        for (int q = 0; q < 4; q++)
            #pragma unroll
            for (int r = 0; r < 4; r++) accfd[m][q][r] = 0.f;

    for (int kp = 0; kp < 4; kp++) {
        const int tb = 3 * kp;
        // slot: compute tile 3kp (buf2), stage tile 3kp+2 -> buf1
        WAITV4;
        STAGEF(tb + 2, 1);
        COMPUTEF64(2, accfd);
        // slot: compute tile 3kp+1 (buf0), stage tile 3kp+3 -> buf2
        WAITV4;
        if (kp < 3) STAGEF(tb + 3, 2);
        COMPUTEF64(0, accfd);
        // slot: compute tile 3kp+2 (buf1), stage tile 3kp+4 -> buf0
        if (kp < 3) {
            WAITV4;
            STAGEF(tb + 4, 0);
        } else {
            WAITV0;
        }
        COMPUTEF64(1, accfd);
    }
#undef STAGECD
#undef STAGEF
#undef COMPUTECD
#undef COMPUTEF64
#undef WAITV4
#undef WAITV0

    // ---- single deferred epilogue: scales + t1 + rowfd + rowrc ----
    // C/D layout: col = lane&15, row = (lane>>4)*4 + reg (dtype-independent)
    float scc_[4], sfc_[4];
    #pragma unroll
    for (int q = 0; q < 4; q++) {
        size_t colp = (size_t)NPTP + (size_t)n * PPAD + bp2 + wn*64 + q*16 + frow;
        scc_[q] = sC[colp];
        sfc_[q] = sF[colp];
    }

    float t1 = 0.f;
    #pragma unroll
    for (int m = 0; m < 4; m++) {
        #pragma unroll
        for (int r = 0; r < 4; r++) {
            size_t rowp = (size_t)n * PPAD + bp1 + wm*64 + m*16 + fcg*4 + r;
            float scr = sC[rowp];
            float sfr = sF[rowp];
            float sf = 0.f, sr = 0.f;
            #pragma unroll
            for (int q = 0; q < 4; q++) {
                float fdv = accfd[m][q][r] * sfr * sfc_[q];
                float rcv = bup(pcd[m][q][r >> 1], r & 1) * scr * scc_[q];
                t1 += rcv * fdv;
                sf += fdv;
                sr += rcv;
            }
            #pragma unroll
            for (int d = 1; d < 16; d <<= 1) {
                sf += __shfl_xor(sf, d, 64);
                sr += __shfl_xor(sr, d, 64);
            }
            if ((lane & 15) == 0) {
                int row = bp1 + wm*64 + m*16 + fcg*4 + r;
                atomicAdd(&rowfd[n * PPAD + row], sf);
                atomicAdd(&rowrc[n * PPAD + row], sr);
            }
        }
    }
    #pragma unroll
    for (int d = 1; d < 64; d <<= 1) t1 += __shfl_xor(t1, d, 64);
    __shared__ float t1s[4];
    if (lane == 0) t1s[wv] = t1;
    __syncthreads();
    if (t == 0) atomicAdd(t1out, t1s[0] + t1s[1] + t1s[2] + t1s[3]);
}

// ---------------------------------------------------------------------------
// Kernel 4: finalize. loss = -(T1 - cross/PP + (Sfd/M)*Src)/M
// ---------------------------------------------------------------------------
__global__ __launch_bounds__(1024) void k_final(
    const float* __restrict__ rowfd, const float* __restrict__ rowrc,
    const float* __restrict__ t1p, float* __restrict__ out)
{
    const int t = threadIdx.x;
    double cr = 0.0, sf = 0.0, sr = 0.0;
    for (int i = t; i < NN * PPAD; i += 1024) {
        double a = rowfd[i], b = rowrc[i];
        cr += a * b; sf += a; sr += b;
    }
    __shared__ double sh[1024];
    sh[t] = cr; __syncthreads();
    for (int s = 512; s > 0; s >>= 1) { if (t < s) sh[t] += sh[t + s]; __syncthreads(); }
    cr = sh[0]; __syncthreads();
    sh[t] = sf; __syncthreads();
    for (int s = 512; s > 0; s >>= 1) { if (t < s) sh[t] += sh[t + s]; __syncthreads(); }
    sf = sh[0]; __syncthreads();
    sh[t] = sr; __syncthreads();
    for (int s = 512; s > 0; s >>= 1) { if (t < s) sh[t] += sh[t + s]; __syncthreads(); }
    sr = sh[0];
    if (t == 0) {
        double M = (double)NN * (double)PP * (double)PP;
        double t1 = (double)t1p[0];
        double bracket = t1 - cr / (double)PP + (sf / M) * sr;
        out[0] = (float)(-bracket / M);
    }
}

// ---------------------------------------------------------------------------
extern "C" void kernel_launch(void* const* d_in, const int* in_sizes, int n_in,
                              void* d_out, int out_size, void* d_ws, size_t ws_size,
                              hipStream_t stream)
{
    const float* orig_feats     = (const float*)d_in[0];
    const float* orig_feats_pos = (const float*)d_in[1];
    const float* orig_code      = (const float*)d_in[2];
    const float* orig_code_pos  = (const float*)d_in[3];
    const float* coords1        = (const float*)d_in[4];
    const float* coords2        = (const float*)d_in[5];

    // ---- workspace layout ----
    char* ws = (char*)d_ws;
    float* t1    = (float*)(ws + 0);                      //      256 B
    float* rowfd = (float*)(ws + 256);                    //  106,496 B (NN*PPAD)
    float* rowrc = (float*)(ws + 106752);                 //  106,496 B
    float* nrmF  = (float*)(ws + 213248);                 //  212,992 B (2*NPTP)
    float* nrmC  = (float*)(ws + 426240);                 //  212,992 B
    const size_t zeroBytes = 639232;                      // t1+rowsums+nrms
    float* sclF  = (float*)(ws + 639232);                 //  212,992 B
    float* sclC  = (float*)(ws + 852224);                 //  212,992 B
    unsigned char* OF0 = (unsigned char*)(ws + 1065216);  // [16][24][4][1664][8B] fp8
    unsigned char* OF1 = (unsigned char*)(ws + 1065216 + 20447232ull);
    short* OC0 = (short*)(ws + 1065216 + 2*20447232ull);  // [16][2][1664][32] bf16
    short* OC1 = (short*)(ws + 1065216 + 2*20447232ull + 3407872ull);

    (void)hipMemsetAsync(d_ws, 0, zeroBytes, stream);   // t1/rowsums/nrms

    k_sample<<<dim3(3328), 256, 0, stream>>>(
        orig_feats, orig_feats_pos, orig_code, orig_code_pos,
        coords1, coords2, nrmF, nrmC, OF0, OF1, OC0, OC1);

    k_nrm<<<dim3((2*NPTP + 255)/256, 2), 256, 0, stream>>>(
        nrmF, nrmC, sclF, sclC);

    k_corr<<<dim3(2704), 256, 0, stream>>>(
        OF0, OF1, OC0, OC1, sclF, sclC, rowfd, rowrc, t1);

    k_final<<<1, 1024, 0, stream>>>(rowfd, rowrc, t1, (float*)d_out);
}